// Round 1
// baseline (908.007 us; speedup 1.0000x reference)
//
#include <hip/hip_runtime.h>
#include <math.h>

// ============================ CSR build ============================

__global__ void zero_int_kernel(int* __restrict__ p, int n) {
  int t = blockIdx.x * blockDim.x + threadIdx.x;
  if (t < n) p[t] = 0;
}

__global__ void hist_kernel(const int* __restrict__ dst, int* __restrict__ deg, int E) {
  int t = blockIdx.x * blockDim.x + threadIdx.x;
  if (t < E) atomicAdd(&deg[dst[t]], 1);
}

// Single-block exclusive scan over N=50000 (49 chunks of 1024). Writes
// offsets[0..N] and a second copy (cursor) used by the scatter pass.
__global__ void scan_kernel(const int* __restrict__ deg, int* __restrict__ offsets,
                            int* __restrict__ cursor, int n) {
  __shared__ int tmp[1024];
  __shared__ int running_s;
  int t = threadIdx.x;
  if (t == 0) running_s = 0;
  __syncthreads();
  for (int base = 0; base < n; base += 1024) {
    int i = base + t;
    int v = (i < n) ? deg[i] : 0;
    tmp[t] = v;
    __syncthreads();
    #pragma unroll
    for (int off = 1; off < 1024; off <<= 1) {
      int add = (t >= off) ? tmp[t - off] : 0;
      __syncthreads();
      tmp[t] += add;
      __syncthreads();
    }
    int run = running_s;           // stable: last update was behind a barrier
    int excl = tmp[t] - v;
    if (i < n) { offsets[i] = run + excl; cursor[i] = run + excl; }
    int tot = tmp[1023];
    __syncthreads();
    if (t == 0) running_s = run + tot;
    __syncthreads();
  }
  if (t == 0) offsets[n] = running_s;
}

__global__ void build_csr_kernel(const int* __restrict__ src, const int* __restrict__ dst,
                                 int* __restrict__ cursor, int* __restrict__ src_sorted,
                                 int* __restrict__ pos_of_edge, int E) {
  int e = blockIdx.x * blockDim.x + threadIdx.x;
  if (e < E) {
    int p = atomicAdd(&cursor[dst[e]], 1);
    src_sorted[p] = src[e];
    pos_of_edge[e] = p;   // inverse permutation: lets score kernel write pre-sorted
  }
}

// ============================ GEMM (fp32, no MFMA on CDNA4) ============================
// C[M,N] = A[M,K] @ B[K,N].  BM=BN=64, BK=16, 256 threads, 4x4 microtile.
// K must be a multiple of 16 (true here: K=256). Handles M tail and N<64.

__global__ __launch_bounds__(256) void gemm_kernel(const float* __restrict__ A,
                                                   const float* __restrict__ B,
                                                   float* __restrict__ C,
                                                   int M, int N, int K) {
  __shared__ float As[16][64];   // transposed A tile: As[k][row]
  __shared__ float Bs[16][64];   // Bs[k][col]
  int t = threadIdx.x;
  int bm0 = blockIdx.x * 64;
  int bn0 = blockIdx.y * 64;
  int tx = t & 15, ty = t >> 4;
  int tm0 = ty * 4, tn0 = tx * 4;
  float acc[4][4] = {};
  int ar = t >> 2, ac4 = (t & 3) * 4;   // A tile load: row ar (0..63), k ac4..ac4+3
  int br = t >> 4, bc4 = (t & 15) * 4;  // B tile load: k-row br (0..15), col bc4..+3

  for (int k0 = 0; k0 < K; k0 += 16) {
    float4 a4 = make_float4(0.f, 0.f, 0.f, 0.f);
    int arow = bm0 + ar;
    if (arow < M) a4 = *(const float4*)(A + (size_t)arow * K + k0 + ac4);
    As[ac4 + 0][ar] = a4.x; As[ac4 + 1][ar] = a4.y;
    As[ac4 + 2][ar] = a4.z; As[ac4 + 3][ar] = a4.w;

    float4 b4 = make_float4(0.f, 0.f, 0.f, 0.f);
    int bcol = bn0 + bc4;
    if (bcol + 3 < N) b4 = *(const float4*)(B + (size_t)(k0 + br) * N + bcol);
    *(float4*)&Bs[br][bc4] = b4;

    __syncthreads();
    #pragma unroll
    for (int kk = 0; kk < 16; ++kk) {
      float4 av = *(const float4*)&As[kk][tm0];
      float4 bv = *(const float4*)&Bs[kk][tn0];
      acc[0][0] += av.x * bv.x; acc[0][1] += av.x * bv.y; acc[0][2] += av.x * bv.z; acc[0][3] += av.x * bv.w;
      acc[1][0] += av.y * bv.x; acc[1][1] += av.y * bv.y; acc[1][2] += av.y * bv.z; acc[1][3] += av.y * bv.w;
      acc[2][0] += av.z * bv.x; acc[2][1] += av.z * bv.y; acc[2][2] += av.z * bv.z; acc[2][3] += av.z * bv.w;
      acc[3][0] += av.w * bv.x; acc[3][1] += av.w * bv.y; acc[3][2] += av.w * bv.z; acc[3][3] += av.w * bv.w;
    }
    __syncthreads();
  }

  #pragma unroll
  for (int i = 0; i < 4; ++i) {
    int row = bm0 + tm0 + i;
    if (row >= M) break;
    int col = bn0 + tn0;
    if (col + 3 < N) {
      float4 v = make_float4(acc[i][0], acc[i][1], acc[i][2], acc[i][3]);
      *(float4*)(C + (size_t)row * N + col) = v;
    } else {
      #pragma unroll
      for (int j = 0; j < 4; ++j)
        if (col + j < N) C[(size_t)row * N + col + j] = acc[i][j];
    }
  }
}

// ============================ attention scalars el/er ============================
// One wave per node: el[n,h] = sum_d z[n,h*D+d]*attn_l[h*D+d]  (same for er).

template<int H, int D>
__global__ void elr_kernel(const float* __restrict__ z, const float* __restrict__ al,
                           const float* __restrict__ ar, float* __restrict__ el,
                           float* __restrict__ er, int n) {
  int wave = blockIdx.x * (blockDim.x >> 6) + (threadIdx.x >> 6);
  int lane = threadIdx.x & 63;
  if (wave >= n) return;
  const float* zr = z + (size_t)wave * (H * D);
  #pragma unroll
  for (int h = 0; h < H; ++h) {
    float pl = 0.f, pr = 0.f;
    if (lane < D) {
      float zv = zr[h * D + lane];
      pl = zv * al[h * D + lane];
      pr = zv * ar[h * D + lane];
    }
    #pragma unroll
    for (int off = 32; off; off >>= 1) {
      pl += __shfl_xor(pl, off);
      pr += __shfl_xor(pr, off);
    }
    if (lane == 0) { el[(size_t)wave * H + h] = pl; er[(size_t)wave * H + h] = pr; }
  }
}

// ============================ edge scores (leaky_relu), written pre-sorted ============================

template<int H>
__global__ void score_kernel(const int* __restrict__ src, const int* __restrict__ dst,
                             const float* __restrict__ el, const float* __restrict__ er,
                             const int* __restrict__ pos, float* __restrict__ score_sorted,
                             int E) {
  int t = blockIdx.x * blockDim.x + threadIdx.x;
  if (t >= E * H) return;
  int e = t / H, h = t % H;
  float v = el[(size_t)src[e] * H + h] + er[(size_t)dst[e] * H + h];
  v = v > 0.f ? v : 0.2f * v;                       // leaky_relu, slope 0.2
  score_sorted[(size_t)h * E + pos[e]] = v;
}

// ============================ softmax + aggregate, one wave per (dst,head) ============================
// CSR groups incoming edges per dst: max & sum are wave-local, zero atomics.
// Lane d owns output component d; per edge one coalesced D-float z[src] read.

template<int H, int D, bool ELU>
__global__ void agg_kernel(const int* __restrict__ offsets, const int* __restrict__ src_sorted,
                           const float* __restrict__ score_sorted, const float* __restrict__ z,
                           const float* __restrict__ bias, float* __restrict__ out,
                           int n, int E) {
  int wave = blockIdx.x * (blockDim.x >> 6) + (threadIdx.x >> 6);
  int lane = threadIdx.x & 63;
  if (wave >= n * H) return;
  int node = wave / H, h = wave % H;
  int s0 = offsets[node], s1 = offsets[node + 1];
  const float* sc = score_sorted + (size_t)h * E;

  float m = -INFINITY;
  for (int i = s0 + lane; i < s1; i += 64) m = fmaxf(m, sc[i]);
  #pragma unroll
  for (int off = 32; off; off >>= 1) m = fmaxf(m, __shfl_xor(m, off));

  float ssum = 0.f, acc = 0.f;
  for (int i = s0; i < s1; ++i) {
    float w = expf(sc[i] - m);      // all lanes compute same w (broadcast load)
    ssum += w;
    int sn = src_sorted[i];
    if (lane < D) acc += w * z[(size_t)sn * (H * D) + h * D + lane];
  }
  float inv = (s1 > s0) ? 1.f / ssum : 0.f;   // deg==0 -> out = bias (matches jax)
  if (lane < D) {
    float o = acc * inv + bias[h * D + lane];
    if (ELU) o = (o > 0.f) ? o : expm1f(o);   // jax.nn.elu, alpha=1
    out[(size_t)node * (H * D) + h * D + lane] = o;
  }
}

// ============================ launch ============================

extern "C" void kernel_launch(void* const* d_in, const int* in_sizes, int n_in,
                              void* d_out, int out_size, void* d_ws, size_t ws_size,
                              hipStream_t stream) {
  const float* x   = (const float*)d_in[0];
  const int*   src = (const int*)d_in[1];
  const int*   dst = (const int*)d_in[2];
  const float* W0  = (const float*)d_in[3];
  const float* al0 = (const float*)d_in[4];
  const float* ar0 = (const float*)d_in[5];
  const float* b0  = (const float*)d_in[6];
  const float* W1  = (const float*)d_in[7];
  const float* al1 = (const float*)d_in[8];
  const float* ar1 = (const float*)d_in[9];
  const float* b1  = (const float*)d_in[10];
  float* out = (float*)d_out;

  const int N = in_sizes[0] / 256;   // 50000
  const int E = in_sizes[1];         // 800000

  char* ws = (char*)d_ws;
  size_t off = 0;
  auto alloc = [&](size_t bytes) {
    void* p = ws + off;
    off = (off + bytes + 255) & ~(size_t)255;
    return p;
  };
  float* z0   = (float*)alloc((size_t)N * 256 * 4);   // layer0 projected feats [N,4,64]
  float* h0   = (float*)alloc((size_t)N * 256 * 4);   // layer0 output (post-ELU) [N,256]
  float* z1   = (float*)alloc((size_t)N * 40 * 4);    // layer1 projected feats [N,40]
  float* el0  = (float*)alloc((size_t)N * 4 * 4);
  float* er0  = (float*)alloc((size_t)N * 4 * 4);
  float* el1  = (float*)alloc((size_t)N * 4);
  float* er1  = (float*)alloc((size_t)N * 4);
  float* sc   = (float*)alloc((size_t)E * 4 * 4);     // scores, [H][E] pre-sorted; reused by layer1
  int* deg    = (int*)alloc((size_t)N * 4);
  int* offs   = (int*)alloc((size_t)(N + 1) * 4);
  int* cursor = (int*)alloc((size_t)N * 4);
  int* ssrc   = (int*)alloc((size_t)E * 4);           // src of dst-sorted edges
  int* pos    = (int*)alloc((size_t)E * 4);           // edge -> sorted position
  (void)off; (void)ws_size; (void)n_in; (void)out_size;

  // ---- CSR (same graph both layers) ----
  zero_int_kernel<<<(N + 255) / 256, 256, 0, stream>>>(deg, N);
  hist_kernel<<<(E + 255) / 256, 256, 0, stream>>>(dst, deg, E);
  scan_kernel<<<1, 1024, 0, stream>>>(deg, offs, cursor, N);
  build_csr_kernel<<<(E + 255) / 256, 256, 0, stream>>>(src, dst, cursor, ssrc, pos, E);

  // ---- layer 0: GATConv(256 -> 4x64) + ELU ----
  gemm_kernel<<<dim3((N + 63) / 64, 4), 256, 0, stream>>>(x, W0, z0, N, 256, 256);
  elr_kernel<4, 64><<<(N + 3) / 4, 256, 0, stream>>>(z0, al0, ar0, el0, er0, N);
  score_kernel<4><<<((E * 4) + 255) / 256, 256, 0, stream>>>(src, dst, el0, er0, pos, sc, E);
  agg_kernel<4, 64, true><<<N, 256, 0, stream>>>(offs, ssrc, sc, z0, b0, h0, N, E);

  // ---- layer 1: GATConv(256 -> 1x40), no activation, head-mean (H=1 -> identity) ----
  gemm_kernel<<<dim3((N + 63) / 64, 1), 256, 0, stream>>>(h0, W1, z1, N, 40, 256);
  elr_kernel<1, 40><<<(N + 3) / 4, 256, 0, stream>>>(z1, al1, ar1, el1, er1, N);
  score_kernel<1><<<(E + 255) / 256, 256, 0, stream>>>(src, dst, el1, er1, pos, sc, E);
  agg_kernel<1, 40, false><<<(N + 3) / 4, 256, 0, stream>>>(offs, ssrc, sc, z1, b1, out, N, E);
}

// Round 4
// 698.269 us; speedup vs baseline: 1.3004x; 1.3004x over previous
//
#include <hip/hip_runtime.h>
#include <math.h>

// ============================ CSR build (proven R1) ============================

__global__ void zero_int_kernel(int* __restrict__ p, int n) {
  int t = blockIdx.x * blockDim.x + threadIdx.x;
  if (t < n) p[t] = 0;
}

__global__ void hist_kernel(const int* __restrict__ dst, int* __restrict__ deg, int E) {
  int t = blockIdx.x * blockDim.x + threadIdx.x;
  if (t < E) atomicAdd(&deg[dst[t]], 1);
}

__global__ void scan_kernel(const int* __restrict__ deg, int* __restrict__ offsets,
                            int* __restrict__ cursor, int n) {
  __shared__ int tmp[1024];
  __shared__ int running_s;
  int t = threadIdx.x;
  if (t == 0) running_s = 0;
  __syncthreads();
  for (int base = 0; base < n; base += 1024) {
    int i = base + t;
    int v = (i < n) ? deg[i] : 0;
    tmp[t] = v;
    __syncthreads();
    #pragma unroll
    for (int off = 1; off < 1024; off <<= 1) {
      int add = (t >= off) ? tmp[t - off] : 0;
      __syncthreads();
      tmp[t] += add;
      __syncthreads();
    }
    int run = running_s;
    int excl = tmp[t] - v;
    if (i < n) { offsets[i] = run + excl; cursor[i] = run + excl; }
    int tot = tmp[1023];
    __syncthreads();
    if (t == 0) running_s = run + tot;
    __syncthreads();
  }
  if (t == 0) offsets[n] = running_s;
}

__global__ void build_csr_kernel(const int* __restrict__ src, const int* __restrict__ dst,
                                 int* __restrict__ cursor, int* __restrict__ src_sorted,
                                 int* __restrict__ pos_of_edge, int E) {
  int e = blockIdx.x * blockDim.x + threadIdx.x;
  if (e < E) {
    int p = atomicAdd(&cursor[dst[e]], 1);
    src_sorted[p] = src[e];
    pos_of_edge[e] = p;
  }
}

// ============================ GEMM (proven R1) ============================

__global__ __launch_bounds__(256) void gemm_kernel(const float* __restrict__ A,
                                                   const float* __restrict__ B,
                                                   float* __restrict__ C,
                                                   int M, int N, int K) {
  __shared__ float As[16][64];
  __shared__ float Bs[16][64];
  int t = threadIdx.x;
  int bm0 = blockIdx.x * 64;
  int bn0 = blockIdx.y * 64;
  int tx = t & 15, ty = t >> 4;
  int tm0 = ty * 4, tn0 = tx * 4;
  float acc[4][4] = {};
  int ar = t >> 2, ac4 = (t & 3) * 4;
  int br = t >> 4, bc4 = (t & 15) * 4;

  for (int k0 = 0; k0 < K; k0 += 16) {
    float4 a4 = make_float4(0.f, 0.f, 0.f, 0.f);
    int arow = bm0 + ar;
    if (arow < M) a4 = *(const float4*)(A + (size_t)arow * K + k0 + ac4);
    As[ac4 + 0][ar] = a4.x; As[ac4 + 1][ar] = a4.y;
    As[ac4 + 2][ar] = a4.z; As[ac4 + 3][ar] = a4.w;

    float4 b4 = make_float4(0.f, 0.f, 0.f, 0.f);
    int bcol = bn0 + bc4;
    if (bcol + 3 < N) b4 = *(const float4*)(B + (size_t)(k0 + br) * N + bcol);
    *(float4*)&Bs[br][bc4] = b4;

    __syncthreads();
    #pragma unroll
    for (int kk = 0; kk < 16; ++kk) {
      float4 av = *(const float4*)&As[kk][tm0];
      float4 bv = *(const float4*)&Bs[kk][tn0];
      acc[0][0] += av.x * bv.x; acc[0][1] += av.x * bv.y; acc[0][2] += av.x * bv.z; acc[0][3] += av.x * bv.w;
      acc[1][0] += av.y * bv.x; acc[1][1] += av.y * bv.y; acc[1][2] += av.y * bv.z; acc[1][3] += av.y * bv.w;
      acc[2][0] += av.z * bv.x; acc[2][1] += av.z * bv.y; acc[2][2] += av.z * bv.z; acc[2][3] += av.z * bv.w;
      acc[3][0] += av.w * bv.x; acc[3][1] += av.w * bv.y; acc[3][2] += av.w * bv.z; acc[3][3] += av.w * bv.w;
    }
    __syncthreads();
  }

  #pragma unroll
  for (int i = 0; i < 4; ++i) {
    int row = bm0 + tm0 + i;
    if (row >= M) break;
    int col = bn0 + tn0;
    if (col + 3 < N) {
      float4 v = make_float4(acc[i][0], acc[i][1], acc[i][2], acc[i][3]);
      *(float4*)(C + (size_t)row * N + col) = v;
    } else {
      #pragma unroll
      for (int j = 0; j < 4; ++j)
        if (col + j < N) C[(size_t)row * N + col + j] = acc[i][j];
    }
  }
}

// ============================ attention scalars el/er (proven R1) ============================

template<int H, int D>
__global__ void elr_kernel(const float* __restrict__ z, const float* __restrict__ al,
                           const float* __restrict__ ar, float* __restrict__ el,
                           float* __restrict__ er, int n) {
  int wave = blockIdx.x * (blockDim.x >> 6) + (threadIdx.x >> 6);
  int lane = threadIdx.x & 63;
  if (wave >= n) return;
  const float* zr = z + (size_t)wave * (H * D);
  #pragma unroll
  for (int h = 0; h < H; ++h) {
    float pl = 0.f, pr = 0.f;
    if (lane < D) {
      float zv = zr[h * D + lane];
      pl = zv * al[h * D + lane];
      pr = zv * ar[h * D + lane];
    }
    #pragma unroll
    for (int off = 32; off; off >>= 1) {
      pl += __shfl_xor(pl, off);
      pr += __shfl_xor(pr, off);
    }
    if (lane == 0) { el[(size_t)wave * H + h] = pl; er[(size_t)wave * H + h] = pr; }
  }
}

// ============================ edge scores for layer 1 (proven R1) ============================

template<int H>
__global__ void score_kernel(const int* __restrict__ src, const int* __restrict__ dst,
                             const float* __restrict__ el, const float* __restrict__ er,
                             const int* __restrict__ pos, float* __restrict__ score_sorted,
                             int E) {
  int t = blockIdx.x * blockDim.x + threadIdx.x;
  if (t >= E * H) return;
  int e = t / H, h = t % H;
  float v = el[(size_t)src[e] * H + h] + er[(size_t)dst[e] * H + h];
  v = v > 0.f ? v : 0.2f * v;
  score_sorted[(size_t)h * E + pos[e]] = v;
}

// ============================ layer-1 aggregation (proven R1) ============================

template<int H, int D, bool ELU>
__global__ void agg_kernel(const int* __restrict__ offsets, const int* __restrict__ src_sorted,
                           const float* __restrict__ score_sorted, const float* __restrict__ z,
                           const float* __restrict__ bias, float* __restrict__ out,
                           int n, int E) {
  int wave = blockIdx.x * (blockDim.x >> 6) + (threadIdx.x >> 6);
  int lane = threadIdx.x & 63;
  if (wave >= n * H) return;
  int node = wave / H, h = wave % H;
  int s0 = offsets[node], s1 = offsets[node + 1];
  const float* sc = score_sorted + (size_t)h * E;

  float m = -INFINITY;
  for (int i = s0 + lane; i < s1; i += 64) m = fmaxf(m, sc[i]);
  #pragma unroll
  for (int off = 32; off; off >>= 1) m = fmaxf(m, __shfl_xor(m, off));

  float ssum = 0.f, acc = 0.f;
  for (int i = s0; i < s1; ++i) {
    float w = expf(sc[i] - m);
    ssum += w;
    int sn = src_sorted[i];
    if (lane < D) acc += w * z[(size_t)sn * (H * D) + h * D + lane];
  }
  float inv = (s1 > s0) ? 1.f / ssum : 0.f;
  if (lane < D) {
    float o = acc * inv + bias[h * D + lane];
    if (ELU) o = (o > 0.f) ? o : expm1f(o);
    out[(size_t)node * (H * D) + h * D + lane] = o;
  }
}

// ============================ layer-0 aggregation: one wave per node, 4 heads fused ============================
// NEW vs R3: weight/source handoff goes through per-wave LDS staging instead of
// arbitrary-index __shfl (the one unproven primitive common to R2/R3 failures).
// Scoring role: lane=(eoff=lane>>2, c=lane&3). Output role: lane owns z dims
// [4*lane, 4*lane+3], head h=lane>>4. Same-wave LDS write->read is ordered by
// the in-order per-wave LDS pipe (wave-synchronous idiom); no __syncthreads.

__global__ __launch_bounds__(256) void agg0_kernel(
    const int* __restrict__ offs, const int* __restrict__ ssrc,
    const float* __restrict__ el, const float* __restrict__ er,
    const float* __restrict__ z, const float* __restrict__ bias,
    float* __restrict__ out, int n) {
  __shared__ float sW[4][16][4];   // [wave][edge slot][head class]
  __shared__ int   sS[4][16];      // [wave][edge slot] -> src node
  int wid  = threadIdx.x >> 6;
  int lane = threadIdx.x & 63;
  int node = blockIdx.x * 4 + wid;
  if (node >= n) return;
  int c = lane & 3, eoff = lane >> 2, h = lane >> 4;
  int s0 = offs[node], s1 = offs[node + 1];
  float er_c = er[node * 4 + c];

  // ---- pass 1: per-class max (proven __shfl_xor butterfly only) ----
  float m = -INFINITY;
  for (int base = s0; base < s1; base += 16) {
    int cnt = min(16, s1 - base);
    if (eoff < cnt) {
      int esrc = ssrc[base + eoff];
      float v = el[esrc * 4 + c] + er_c;
      v = v > 0.f ? v : 0.2f * v;            // leaky_relu(0.2)
      m = fmaxf(m, v);
    }
  }
  m = fmaxf(m, __shfl_xor(m, 4));            // reduce over eoff bits 2..5
  m = fmaxf(m, __shfl_xor(m, 8));
  m = fmaxf(m, __shfl_xor(m, 16));
  m = fmaxf(m, __shfl_xor(m, 32));           // every lane: max for class c

  // ---- pass 2: stage weights in LDS, then broadcast-read + gather ----
  float ssum = 0.f;
  float4 acc = make_float4(0.f, 0.f, 0.f, 0.f);
  for (int base = s0; base < s1; base += 16) {
    int cnt = min(16, s1 - base);
    if (eoff < cnt) {
      int esrc = ssrc[base + eoff];
      float v = el[esrc * 4 + c] + er_c;
      v = v > 0.f ? v : 0.2f * v;
      sW[wid][eoff][c] = expf(v - m);        // fixed m: no rescaling
      if (c == 0) sS[wid][eoff] = esrc;
    }
    for (int j = 0; j < cnt; ++j) {
      float w  = sW[wid][j][h];              // same-address broadcast per 16-lane group
      int   sn = sS[wid][j];                 // wave-uniform broadcast
      ssum += w;                             // per-lane denom for head h
      const float4 zv = *(const float4*)(z + (size_t)sn * 256 + (lane << 2));
      acc.x += w * zv.x; acc.y += w * zv.y; acc.z += w * zv.z; acc.w += w * zv.w;
    }
  }

  float inv = (s1 > s0) ? 1.f / ssum : 0.f;  // deg==0 -> out = bias (matches jax)
  const float4 b4 = *(const float4*)(bias + (lane << 2));
  float4 o;
  o.x = acc.x * inv + b4.x;
  o.y = acc.y * inv + b4.y;
  o.z = acc.z * inv + b4.z;
  o.w = acc.w * inv + b4.w;
  o.x = o.x > 0.f ? o.x : expm1f(o.x);       // ELU (alpha=1)
  o.y = o.y > 0.f ? o.y : expm1f(o.y);
  o.z = o.z > 0.f ? o.z : expm1f(o.z);
  o.w = o.w > 0.f ? o.w : expm1f(o.w);
  *(float4*)(out + (size_t)node * 256 + (lane << 2)) = o;
}

// ============================ launch ============================

extern "C" void kernel_launch(void* const* d_in, const int* in_sizes, int n_in,
                              void* d_out, int out_size, void* d_ws, size_t ws_size,
                              hipStream_t stream) {
  const float* x   = (const float*)d_in[0];
  const int*   src = (const int*)d_in[1];
  const int*   dst = (const int*)d_in[2];
  const float* W0  = (const float*)d_in[3];
  const float* al0 = (const float*)d_in[4];
  const float* ar0 = (const float*)d_in[5];
  const float* b0  = (const float*)d_in[6];
  const float* W1  = (const float*)d_in[7];
  const float* al1 = (const float*)d_in[8];
  const float* ar1 = (const float*)d_in[9];
  const float* b1  = (const float*)d_in[10];
  float* out = (float*)d_out;

  const int N = in_sizes[0] / 256;   // 50000
  const int E = in_sizes[1];         // 800000

  char* ws = (char*)d_ws;
  size_t off = 0;
  auto alloc = [&](size_t bytes) {
    void* p = ws + off;
    off = (off + bytes + 255) & ~(size_t)255;
    return p;
  };
  float* z0   = (float*)alloc((size_t)N * 256 * 4);
  float* h0   = (float*)alloc((size_t)N * 256 * 4);
  float* z1   = (float*)alloc((size_t)N * 40 * 4);
  float* el0  = (float*)alloc((size_t)N * 4 * 4);
  float* er0  = (float*)alloc((size_t)N * 4 * 4);
  float* el1  = (float*)alloc((size_t)N * 4);
  float* er1  = (float*)alloc((size_t)N * 4);
  float* sc1  = (float*)alloc((size_t)E * 4);        // layer-1 scores (H=1), pre-sorted
  int* deg    = (int*)alloc((size_t)N * 4);
  int* offs   = (int*)alloc((size_t)(N + 1) * 4);
  int* cursor = (int*)alloc((size_t)N * 4);
  int* ssrc   = (int*)alloc((size_t)E * 4);
  int* pos    = (int*)alloc((size_t)E * 4);
  (void)off; (void)ws_size; (void)n_in; (void)out_size;

  // ---- CSR (same graph both layers) ----
  zero_int_kernel<<<(N + 255) / 256, 256, 0, stream>>>(deg, N);
  hist_kernel<<<(E + 255) / 256, 256, 0, stream>>>(dst, deg, E);
  scan_kernel<<<1, 1024, 0, stream>>>(deg, offs, cursor, N);
  build_csr_kernel<<<(E + 255) / 256, 256, 0, stream>>>(src, dst, cursor, ssrc, pos, E);

  // ---- layer 0: GATConv(256 -> 4x64) + ELU (new fused agg0) ----
  gemm_kernel<<<dim3((N + 63) / 64, 4), 256, 0, stream>>>(x, W0, z0, N, 256, 256);
  elr_kernel<4, 64><<<(N + 3) / 4, 256, 0, stream>>>(z0, al0, ar0, el0, er0, N);
  agg0_kernel<<<(N + 3) / 4, 256, 0, stream>>>(offs, ssrc, el0, er0, z0, b0, h0, N);

  // ---- layer 1: GATConv(256 -> 1x40), proven R1 path ----
  gemm_kernel<<<dim3((N + 63) / 64, 1), 256, 0, stream>>>(h0, W1, z1, N, 40, 256);
  elr_kernel<1, 40><<<(N + 3) / 4, 256, 0, stream>>>(z1, al1, ar1, el1, er1, N);
  score_kernel<1><<<(E + 255) / 256, 256, 0, stream>>>(src, dst, el1, er1, pos, sc1, E);
  agg_kernel<1, 40, false><<<(N + 3) / 4, 256, 0, stream>>>(offs, ssrc, sc1, z1, b1, out, N, E);
}

// Round 5
// 527.906 us; speedup vs baseline: 1.7200x; 1.3227x over previous
//
#include <hip/hip_runtime.h>
#include <math.h>

// ============================ CSR build ============================

__global__ void zero_int_kernel(int* __restrict__ p, int n) {
  int t = blockIdx.x * blockDim.x + threadIdx.x;
  if (t < n) p[t] = 0;
}

__global__ void hist_kernel(const int* __restrict__ dst, int* __restrict__ deg, int E) {
  int t = blockIdx.x * blockDim.x + threadIdx.x;
  if (t < E) atomicAdd(&deg[dst[t]], 1);
}

// --- 3-phase parallel exclusive scan (proven-idiom primitives only) ---

__global__ void block_sum_kernel(const int* __restrict__ deg, int* __restrict__ bsum, int n) {
  __shared__ int red[4];
  int t = threadIdx.x, i = blockIdx.x * 256 + t;
  int v = (i < n) ? deg[i] : 0;
  #pragma unroll
  for (int off = 32; off; off >>= 1) v += __shfl_xor(v, off);
  if ((t & 63) == 0) red[t >> 6] = v;
  __syncthreads();
  if (t == 0) bsum[blockIdx.x] = red[0] + red[1] + red[2] + red[3];
}

__global__ void scan_bsum_kernel(const int* __restrict__ bsum, int* __restrict__ boffs,
                                 int* __restrict__ offsets, int nb, int n) {
  __shared__ int tmp[1024];
  int t = threadIdx.x;
  int v = (t < nb) ? bsum[t] : 0;
  tmp[t] = v;
  __syncthreads();
  #pragma unroll
  for (int off = 1; off < 1024; off <<= 1) {
    int add = (t >= off) ? tmp[t - off] : 0;
    __syncthreads();
    tmp[t] += add;
    __syncthreads();
  }
  if (t < nb) boffs[t] = tmp[t] - v;       // exclusive block offset
  if (t == 1023) offsets[n] = tmp[1023];   // total = E
}

__global__ void write_offsets_kernel(const int* __restrict__ deg, const int* __restrict__ boffs,
                                     int* __restrict__ offsets, int* __restrict__ cursor, int n) {
  __shared__ int tmp[256];
  int t = threadIdx.x, i = blockIdx.x * 256 + t;
  int v = (i < n) ? deg[i] : 0;
  tmp[t] = v;
  __syncthreads();
  #pragma unroll
  for (int off = 1; off < 256; off <<= 1) {
    int add = (t >= off) ? tmp[t - off] : 0;
    __syncthreads();
    tmp[t] += add;
    __syncthreads();
  }
  if (i < n) {
    int o = boffs[blockIdx.x] + tmp[t] - v;
    offsets[i] = o;
    cursor[i] = o;
  }
}

__global__ void build_csr_kernel(const int* __restrict__ src, const int* __restrict__ dst,
                                 int* __restrict__ cursor, int* __restrict__ src_sorted, int E) {
  int e = blockIdx.x * blockDim.x + threadIdx.x;
  if (e < E) {
    int p = atomicAdd(&cursor[dst[e]], 1);
    src_sorted[p] = src[e];
  }
}

// ============================ GEMM (proven R1) ============================

__global__ __launch_bounds__(256) void gemm_kernel(const float* __restrict__ A,
                                                   const float* __restrict__ B,
                                                   float* __restrict__ C,
                                                   int M, int N, int K) {
  __shared__ float As[16][64];
  __shared__ float Bs[16][64];
  int t = threadIdx.x;
  int bm0 = blockIdx.x * 64;
  int bn0 = blockIdx.y * 64;
  int tx = t & 15, ty = t >> 4;
  int tm0 = ty * 4, tn0 = tx * 4;
  float acc[4][4] = {};
  int ar = t >> 2, ac4 = (t & 3) * 4;
  int br = t >> 4, bc4 = (t & 15) * 4;

  for (int k0 = 0; k0 < K; k0 += 16) {
    float4 a4 = make_float4(0.f, 0.f, 0.f, 0.f);
    int arow = bm0 + ar;
    if (arow < M) a4 = *(const float4*)(A + (size_t)arow * K + k0 + ac4);
    As[ac4 + 0][ar] = a4.x; As[ac4 + 1][ar] = a4.y;
    As[ac4 + 2][ar] = a4.z; As[ac4 + 3][ar] = a4.w;

    float4 b4 = make_float4(0.f, 0.f, 0.f, 0.f);
    int bcol = bn0 + bc4;
    if (bcol + 3 < N) b4 = *(const float4*)(B + (size_t)(k0 + br) * N + bcol);
    *(float4*)&Bs[br][bc4] = b4;

    __syncthreads();
    #pragma unroll
    for (int kk = 0; kk < 16; ++kk) {
      float4 av = *(const float4*)&As[kk][tm0];
      float4 bv = *(const float4*)&Bs[kk][tn0];
      acc[0][0] += av.x * bv.x; acc[0][1] += av.x * bv.y; acc[0][2] += av.x * bv.z; acc[0][3] += av.x * bv.w;
      acc[1][0] += av.y * bv.x; acc[1][1] += av.y * bv.y; acc[1][2] += av.y * bv.z; acc[1][3] += av.y * bv.w;
      acc[2][0] += av.z * bv.x; acc[2][1] += av.z * bv.y; acc[2][2] += av.z * bv.z; acc[2][3] += av.z * bv.w;
      acc[3][0] += av.w * bv.x; acc[3][1] += av.w * bv.y; acc[3][2] += av.w * bv.z; acc[3][3] += av.w * bv.w;
    }
    __syncthreads();
  }

  #pragma unroll
  for (int i = 0; i < 4; ++i) {
    int row = bm0 + tm0 + i;
    if (row >= M) break;
    int col = bn0 + tn0;
    if (col + 3 < N) {
      float4 v = make_float4(acc[i][0], acc[i][1], acc[i][2], acc[i][3]);
      *(float4*)(C + (size_t)row * N + col) = v;
    } else {
      #pragma unroll
      for (int j = 0; j < 4; ++j)
        if (col + j < N) C[(size_t)row * N + col + j] = acc[i][j];
    }
  }
}

// ============================ attention scalars el/er (proven R1) ============================

template<int H, int D>
__global__ void elr_kernel(const float* __restrict__ z, const float* __restrict__ al,
                           const float* __restrict__ ar, float* __restrict__ el,
                           float* __restrict__ er, int n) {
  int wave = blockIdx.x * (blockDim.x >> 6) + (threadIdx.x >> 6);
  int lane = threadIdx.x & 63;
  if (wave >= n) return;
  const float* zr = z + (size_t)wave * (H * D);
  #pragma unroll
  for (int h = 0; h < H; ++h) {
    float pl = 0.f, pr = 0.f;
    if (lane < D) {
      float zv = zr[h * D + lane];
      pl = zv * al[h * D + lane];
      pr = zv * ar[h * D + lane];
    }
    #pragma unroll
    for (int off = 32; off; off >>= 1) {
      pl += __shfl_xor(pl, off);
      pr += __shfl_xor(pr, off);
    }
    if (lane == 0) { el[(size_t)wave * H + h] = pl; er[(size_t)wave * H + h] = pr; }
  }
}

// ============================ layer-0 aggregation (proven R4) ============================
// One wave per node, 4 heads fused, two-pass softmax, LDS weight handoff.

__global__ __launch_bounds__(256) void agg0_kernel(
    const int* __restrict__ offs, const int* __restrict__ ssrc,
    const float* __restrict__ el, const float* __restrict__ er,
    const float* __restrict__ z, const float* __restrict__ bias,
    float* __restrict__ out, int n) {
  __shared__ float sW[4][16][4];   // [wave][edge slot][head class]
  __shared__ int   sS[4][16];      // [wave][edge slot] -> src node
  int wid  = threadIdx.x >> 6;
  int lane = threadIdx.x & 63;
  int node = blockIdx.x * 4 + wid;
  if (node >= n) return;
  int c = lane & 3, eoff = lane >> 2, h = lane >> 4;
  int s0 = offs[node], s1 = offs[node + 1];
  float er_c = er[node * 4 + c];

  // ---- pass 1: per-class max ----
  float m = -INFINITY;
  for (int base = s0; base < s1; base += 16) {
    int cnt = min(16, s1 - base);
    if (eoff < cnt) {
      int esrc = ssrc[base + eoff];
      float v = el[esrc * 4 + c] + er_c;
      v = v > 0.f ? v : 0.2f * v;            // leaky_relu(0.2)
      m = fmaxf(m, v);
    }
  }
  m = fmaxf(m, __shfl_xor(m, 4));
  m = fmaxf(m, __shfl_xor(m, 8));
  m = fmaxf(m, __shfl_xor(m, 16));
  m = fmaxf(m, __shfl_xor(m, 32));

  // ---- pass 2: stage weights in LDS, broadcast-read + gather ----
  float ssum = 0.f;
  float4 acc = make_float4(0.f, 0.f, 0.f, 0.f);
  for (int base = s0; base < s1; base += 16) {
    int cnt = min(16, s1 - base);
    if (eoff < cnt) {
      int esrc = ssrc[base + eoff];
      float v = el[esrc * 4 + c] + er_c;
      v = v > 0.f ? v : 0.2f * v;
      sW[wid][eoff][c] = expf(v - m);
      if (c == 0) sS[wid][eoff] = esrc;
    }
    for (int j = 0; j < cnt; ++j) {
      float w  = sW[wid][j][h];
      int   sn = sS[wid][j];
      ssum += w;
      const float4 zv = *(const float4*)(z + (size_t)sn * 256 + (lane << 2));
      acc.x += w * zv.x; acc.y += w * zv.y; acc.z += w * zv.z; acc.w += w * zv.w;
    }
  }

  float inv = (s1 > s0) ? 1.f / ssum : 0.f;
  const float4 b4 = *(const float4*)(bias + (lane << 2));
  float4 o;
  o.x = acc.x * inv + b4.x;
  o.y = acc.y * inv + b4.y;
  o.z = acc.z * inv + b4.z;
  o.w = acc.w * inv + b4.w;
  o.x = o.x > 0.f ? o.x : expm1f(o.x);       // ELU
  o.y = o.y > 0.f ? o.y : expm1f(o.y);
  o.z = o.z > 0.f ? o.z : expm1f(o.z);
  o.w = o.w > 0.f ? o.w : expm1f(o.w);
  *(float4*)(out + (size_t)node * 256 + (lane << 2)) = o;
}

// ============================ layer-1 aggregation: agg0 pattern, H=1, D=40 ============================
// One wave per node; chunk of 64 edges; scores in-register; LDS handoff; no
// score array, no pos permutation. Lanes 0..39 own output dims.

__global__ __launch_bounds__(256) void agg1_kernel(
    const int* __restrict__ offs, const int* __restrict__ ssrc,
    const float* __restrict__ el, const float* __restrict__ er,
    const float* __restrict__ z, const float* __restrict__ bias,
    float* __restrict__ out, int n) {
  __shared__ float sW[4][64];
  __shared__ int   sS[4][64];
  int wid  = threadIdx.x >> 6;
  int lane = threadIdx.x & 63;
  int node = blockIdx.x * 4 + wid;
  if (node >= n) return;
  int s0 = offs[node], s1 = offs[node + 1];
  float ern = er[node];

  // ---- pass 1: wave-wide max ----
  float m = -INFINITY;
  for (int base = s0; base < s1; base += 64) {
    int i = base + lane;
    if (i < s1) {
      float v = el[ssrc[i]] + ern;
      v = v > 0.f ? v : 0.2f * v;
      m = fmaxf(m, v);
    }
  }
  m = fmaxf(m, __shfl_xor(m, 1));
  m = fmaxf(m, __shfl_xor(m, 2));
  m = fmaxf(m, __shfl_xor(m, 4));
  m = fmaxf(m, __shfl_xor(m, 8));
  m = fmaxf(m, __shfl_xor(m, 16));
  m = fmaxf(m, __shfl_xor(m, 32));

  // ---- pass 2: stage weights, broadcast-read + gather ----
  float ssum = 0.f, acc = 0.f;
  for (int base = s0; base < s1; base += 64) {
    int cnt = min(64, s1 - base);
    if (lane < cnt) {
      int esrc = ssrc[base + lane];
      float v = el[esrc] + ern;
      v = v > 0.f ? v : 0.2f * v;
      sW[wid][lane] = expf(v - m);
      sS[wid][lane] = esrc;
    }
    for (int j = 0; j < cnt; ++j) {
      float w  = sW[wid][j];
      int   sn = sS[wid][j];
      ssum += w;
      if (lane < 40) acc += w * z[(size_t)sn * 40 + lane];
    }
  }

  float inv = (s1 > s0) ? 1.f / ssum : 0.f;
  if (lane < 40)
    out[(size_t)node * 40 + lane] = acc * inv + bias[lane];
}

// ============================ launch ============================

extern "C" void kernel_launch(void* const* d_in, const int* in_sizes, int n_in,
                              void* d_out, int out_size, void* d_ws, size_t ws_size,
                              hipStream_t stream) {
  const float* x   = (const float*)d_in[0];
  const int*   src = (const int*)d_in[1];
  const int*   dst = (const int*)d_in[2];
  const float* W0  = (const float*)d_in[3];
  const float* al0 = (const float*)d_in[4];
  const float* ar0 = (const float*)d_in[5];
  const float* b0  = (const float*)d_in[6];
  const float* W1  = (const float*)d_in[7];
  const float* al1 = (const float*)d_in[8];
  const float* ar1 = (const float*)d_in[9];
  const float* b1  = (const float*)d_in[10];
  float* out = (float*)d_out;

  const int N = in_sizes[0] / 256;   // 50000
  const int E = in_sizes[1];         // 800000
  const int NB = (N + 255) / 256;    // 196 scan blocks

  char* ws = (char*)d_ws;
  size_t off = 0;
  auto alloc = [&](size_t bytes) {
    void* p = ws + off;
    off = (off + bytes + 255) & ~(size_t)255;
    return p;
  };
  float* z0   = (float*)alloc((size_t)N * 256 * 4);
  float* h0   = (float*)alloc((size_t)N * 256 * 4);
  float* z1   = (float*)alloc((size_t)N * 40 * 4);
  float* el0  = (float*)alloc((size_t)N * 4 * 4);
  float* er0  = (float*)alloc((size_t)N * 4 * 4);
  float* el1  = (float*)alloc((size_t)N * 4);
  float* er1  = (float*)alloc((size_t)N * 4);
  int* deg    = (int*)alloc((size_t)N * 4);
  int* offs   = (int*)alloc((size_t)(N + 1) * 4);
  int* cursor = (int*)alloc((size_t)N * 4);
  int* bsum   = (int*)alloc((size_t)NB * 4);
  int* boffs  = (int*)alloc((size_t)NB * 4);
  int* ssrc   = (int*)alloc((size_t)E * 4);
  (void)off; (void)ws_size; (void)n_in; (void)out_size;

  // ---- CSR (same graph both layers), parallel scan ----
  zero_int_kernel<<<(N + 255) / 256, 256, 0, stream>>>(deg, N);
  hist_kernel<<<(E + 255) / 256, 256, 0, stream>>>(dst, deg, E);
  block_sum_kernel<<<NB, 256, 0, stream>>>(deg, bsum, N);
  scan_bsum_kernel<<<1, 1024, 0, stream>>>(bsum, boffs, offs, NB, N);
  write_offsets_kernel<<<NB, 256, 0, stream>>>(deg, boffs, offs, cursor, N);
  build_csr_kernel<<<(E + 255) / 256, 256, 0, stream>>>(src, dst, cursor, ssrc, E);

  // ---- layer 0: GATConv(256 -> 4x64) + ELU ----
  gemm_kernel<<<dim3((N + 63) / 64, 4), 256, 0, stream>>>(x, W0, z0, N, 256, 256);
  elr_kernel<4, 64><<<(N + 3) / 4, 256, 0, stream>>>(z0, al0, ar0, el0, er0, N);
  agg0_kernel<<<(N + 3) / 4, 256, 0, stream>>>(offs, ssrc, el0, er0, z0, b0, h0, N);

  // ---- layer 1: GATConv(256 -> 1x40), head-mean (H=1 -> identity) ----
  gemm_kernel<<<dim3((N + 63) / 64, 1), 256, 0, stream>>>(h0, W1, z1, N, 40, 256);
  elr_kernel<1, 40><<<(N + 3) / 4, 256, 0, stream>>>(z1, al1, ar1, el1, er1, N);
  agg1_kernel<<<(N + 3) / 4, 256, 0, stream>>>(offs, ssrc, el1, er1, z1, b1, out, N);
}

// Round 6
// 490.003 us; speedup vs baseline: 1.8531x; 1.0774x over previous
//
#include <hip/hip_runtime.h>
#include <math.h>

// ---- bf16 helpers ----
__device__ __forceinline__ unsigned short f2bf(float v) {          // RNE pack
  unsigned int b = __float_as_uint(v);
  unsigned int r = (b + 0x7fffu + ((b >> 16) & 1u)) >> 16;
  return (unsigned short)r;
}
__device__ __forceinline__ float bf2f(unsigned short u) {
  return __uint_as_float(((unsigned int)u) << 16);
}

// ============================ CSR build (proven R5) ============================

__global__ void zero_int_kernel(int* __restrict__ p, int n) {
  int t = blockIdx.x * blockDim.x + threadIdx.x;
  if (t < n) p[t] = 0;
}

__global__ void hist_kernel(const int* __restrict__ dst, int* __restrict__ deg, int E) {
  int t = blockIdx.x * blockDim.x + threadIdx.x;
  if (t < E) atomicAdd(&deg[dst[t]], 1);
}

__global__ void block_sum_kernel(const int* __restrict__ deg, int* __restrict__ bsum, int n) {
  __shared__ int red[4];
  int t = threadIdx.x, i = blockIdx.x * 256 + t;
  int v = (i < n) ? deg[i] : 0;
  #pragma unroll
  for (int off = 32; off; off >>= 1) v += __shfl_xor(v, off);
  if ((t & 63) == 0) red[t >> 6] = v;
  __syncthreads();
  if (t == 0) bsum[blockIdx.x] = red[0] + red[1] + red[2] + red[3];
}

__global__ void scan_bsum_kernel(const int* __restrict__ bsum, int* __restrict__ boffs,
                                 int* __restrict__ offsets, int nb, int n) {
  __shared__ int tmp[1024];
  int t = threadIdx.x;
  int v = (t < nb) ? bsum[t] : 0;
  tmp[t] = v;
  __syncthreads();
  #pragma unroll
  for (int off = 1; off < 1024; off <<= 1) {
    int add = (t >= off) ? tmp[t - off] : 0;
    __syncthreads();
    tmp[t] += add;
    __syncthreads();
  }
  if (t < nb) boffs[t] = tmp[t] - v;
  if (t == 1023) offsets[n] = tmp[1023];
}

__global__ void write_offsets_kernel(const int* __restrict__ deg, const int* __restrict__ boffs,
                                     int* __restrict__ offsets, int* __restrict__ cursor, int n) {
  __shared__ int tmp[256];
  int t = threadIdx.x, i = blockIdx.x * 256 + t;
  int v = (i < n) ? deg[i] : 0;
  tmp[t] = v;
  __syncthreads();
  #pragma unroll
  for (int off = 1; off < 256; off <<= 1) {
    int add = (t >= off) ? tmp[t - off] : 0;
    __syncthreads();
    tmp[t] += add;
    __syncthreads();
  }
  if (i < n) {
    int o = boffs[blockIdx.x] + tmp[t] - v;
    offsets[i] = o;
    cursor[i] = o;
  }
}

__global__ void build_csr_kernel(const int* __restrict__ src, const int* __restrict__ dst,
                                 int* __restrict__ cursor, int* __restrict__ src_sorted, int E) {
  int e = blockIdx.x * blockDim.x + threadIdx.x;
  if (e < E) {
    int p = atomicAdd(&cursor[dst[e]], 1);
    src_sorted[p] = src[e];
  }
}

// ============================ GEMM 64-tile (proven R1) + optional bf16 aux output ============================

__global__ __launch_bounds__(256) void gemm_kernel(const float* __restrict__ A,
                                                   const float* __restrict__ B,
                                                   float* __restrict__ C,
                                                   unsigned short* __restrict__ Cb,
                                                   int M, int N, int K) {
  __shared__ float As[16][64];
  __shared__ float Bs[16][64];
  int t = threadIdx.x;
  int bm0 = blockIdx.x * 64;
  int bn0 = blockIdx.y * 64;
  int tx = t & 15, ty = t >> 4;
  int tm0 = ty * 4, tn0 = tx * 4;
  float acc[4][4] = {};
  int ar = t >> 2, ac4 = (t & 3) * 4;
  int br = t >> 4, bc4 = (t & 15) * 4;

  for (int k0 = 0; k0 < K; k0 += 16) {
    float4 a4 = make_float4(0.f, 0.f, 0.f, 0.f);
    int arow = bm0 + ar;
    if (arow < M) a4 = *(const float4*)(A + (size_t)arow * K + k0 + ac4);
    As[ac4 + 0][ar] = a4.x; As[ac4 + 1][ar] = a4.y;
    As[ac4 + 2][ar] = a4.z; As[ac4 + 3][ar] = a4.w;

    float4 b4 = make_float4(0.f, 0.f, 0.f, 0.f);
    int bcol = bn0 + bc4;
    if (bcol + 3 < N) b4 = *(const float4*)(B + (size_t)(k0 + br) * N + bcol);
    *(float4*)&Bs[br][bc4] = b4;

    __syncthreads();
    #pragma unroll
    for (int kk = 0; kk < 16; ++kk) {
      float4 av = *(const float4*)&As[kk][tm0];
      float4 bv = *(const float4*)&Bs[kk][tn0];
      acc[0][0] += av.x * bv.x; acc[0][1] += av.x * bv.y; acc[0][2] += av.x * bv.z; acc[0][3] += av.x * bv.w;
      acc[1][0] += av.y * bv.x; acc[1][1] += av.y * bv.y; acc[1][2] += av.y * bv.z; acc[1][3] += av.y * bv.w;
      acc[2][0] += av.z * bv.x; acc[2][1] += av.z * bv.y; acc[2][2] += av.z * bv.z; acc[2][3] += av.z * bv.w;
      acc[3][0] += av.w * bv.x; acc[3][1] += av.w * bv.y; acc[3][2] += av.w * bv.z; acc[3][3] += av.w * bv.w;
    }
    __syncthreads();
  }

  #pragma unroll
  for (int i = 0; i < 4; ++i) {
    int row = bm0 + tm0 + i;
    if (row >= M) break;
    int col = bn0 + tn0;
    if (col + 3 < N) {
      float4 v = make_float4(acc[i][0], acc[i][1], acc[i][2], acc[i][3]);
      *(float4*)(C + (size_t)row * N + col) = v;
      if (Cb) {
        ushort4 u;
        u.x = f2bf(acc[i][0]); u.y = f2bf(acc[i][1]);
        u.z = f2bf(acc[i][2]); u.w = f2bf(acc[i][3]);
        *(ushort4*)(Cb + (size_t)row * N + col) = u;
      }
    } else {
      #pragma unroll
      for (int j = 0; j < 4; ++j)
        if (col + j < N) {
          C[(size_t)row * N + col + j] = acc[i][j];
          if (Cb) Cb[(size_t)row * N + col + j] = f2bf(acc[i][j]);
        }
    }
  }
}

// ============================ GEMM 128-tile, 8x8 microtile (for the big layer-0 GEMM) ============================
// 256 threads, BM=BN=128, BK=16. 64 FMA per 4 ds_read_b128 -> VALU-bound.

__global__ __launch_bounds__(256) void gemm128_kernel(const float* __restrict__ A,
                                                      const float* __restrict__ B,
                                                      float* __restrict__ C,
                                                      unsigned short* __restrict__ Cb,
                                                      int M, int N, int K) {
  __shared__ float As[16][128];   // As[k][row]
  __shared__ float Bs[16][128];   // Bs[k][col]
  int t = threadIdx.x;
  int bm0 = blockIdx.x * 128;
  int bn0 = blockIdx.y * 128;
  int tx = t & 15, ty = t >> 4;
  int tm0 = ty * 8, tn0 = tx * 8;
  float acc[8][8] = {};
  // A tile: 128 rows x 16 k = 512 float4; thread loads f4 #t and #(t+256)
  int ar0 = t >> 2, ac4 = (t & 3) * 4;        // f4 idx t: row t>>2, kcol (t&3)*4
  // B tile: 16 k x 128 cols = 512 float4; f4 idx f: krow f>>5, col (f&31)*4
  int brA = t >> 5, bcA = (t & 31) * 4;
  int brB = brA + 8;                           // f = t + 256

  for (int k0 = 0; k0 < K; k0 += 16) {
    float4 a4 = make_float4(0.f, 0.f, 0.f, 0.f);
    int arow = bm0 + ar0;
    if (arow < M) a4 = *(const float4*)(A + (size_t)arow * K + k0 + ac4);
    As[ac4 + 0][ar0] = a4.x; As[ac4 + 1][ar0] = a4.y;
    As[ac4 + 2][ar0] = a4.z; As[ac4 + 3][ar0] = a4.w;
    float4 a4b = make_float4(0.f, 0.f, 0.f, 0.f);
    int arow2 = bm0 + ar0 + 64;
    if (arow2 < M) a4b = *(const float4*)(A + (size_t)arow2 * K + k0 + ac4);
    As[ac4 + 0][ar0 + 64] = a4b.x; As[ac4 + 1][ar0 + 64] = a4b.y;
    As[ac4 + 2][ar0 + 64] = a4b.z; As[ac4 + 3][ar0 + 64] = a4b.w;

    float4 b4 = make_float4(0.f, 0.f, 0.f, 0.f);
    int bcol = bn0 + bcA;
    if (bcol + 3 < N) b4 = *(const float4*)(B + (size_t)(k0 + brA) * N + bcol);
    *(float4*)&Bs[brA][bcA] = b4;
    float4 b4b = make_float4(0.f, 0.f, 0.f, 0.f);
    if (bcol + 3 < N) b4b = *(const float4*)(B + (size_t)(k0 + brB) * N + bcol);
    *(float4*)&Bs[brB][bcA] = b4b;

    __syncthreads();
    #pragma unroll
    for (int kk = 0; kk < 16; ++kk) {
      float4 a0 = *(const float4*)&As[kk][tm0];
      float4 a1 = *(const float4*)&As[kk][tm0 + 4];
      float4 b0 = *(const float4*)&Bs[kk][tn0];
      float4 b1 = *(const float4*)&Bs[kk][tn0 + 4];
      float av[8] = {a0.x, a0.y, a0.z, a0.w, a1.x, a1.y, a1.z, a1.w};
      float bv[8] = {b0.x, b0.y, b0.z, b0.w, b1.x, b1.y, b1.z, b1.w};
      #pragma unroll
      for (int i = 0; i < 8; ++i)
        #pragma unroll
        for (int j = 0; j < 8; ++j)
          acc[i][j] += av[i] * bv[j];
    }
    __syncthreads();
  }

  #pragma unroll
  for (int i = 0; i < 8; ++i) {
    int row = bm0 + tm0 + i;
    if (row >= M) break;
    #pragma unroll
    for (int half = 0; half < 2; ++half) {
      int col = bn0 + tn0 + half * 4;
      if (col + 3 < N) {
        float4 v = make_float4(acc[i][half * 4], acc[i][half * 4 + 1],
                               acc[i][half * 4 + 2], acc[i][half * 4 + 3]);
        *(float4*)(C + (size_t)row * N + col) = v;
        if (Cb) {
          ushort4 u;
          u.x = f2bf(v.x); u.y = f2bf(v.y); u.z = f2bf(v.z); u.w = f2bf(v.w);
          *(ushort4*)(Cb + (size_t)row * N + col) = u;
        }
      } else {
        #pragma unroll
        for (int j = 0; j < 4; ++j)
          if (col + j < N) {
            C[(size_t)row * N + col + j] = acc[i][half * 4 + j];
            if (Cb) Cb[(size_t)row * N + col + j] = f2bf(acc[i][half * 4 + j]);
          }
      }
    }
  }
}

// ============================ attention scalars el/er (proven R1; reads fp32 z) ============================

template<int H, int D>
__global__ void elr_kernel(const float* __restrict__ z, const float* __restrict__ al,
                           const float* __restrict__ ar, float* __restrict__ el,
                           float* __restrict__ er, int n) {
  int wave = blockIdx.x * (blockDim.x >> 6) + (threadIdx.x >> 6);
  int lane = threadIdx.x & 63;
  if (wave >= n) return;
  const float* zr = z + (size_t)wave * (H * D);
  #pragma unroll
  for (int h = 0; h < H; ++h) {
    float pl = 0.f, pr = 0.f;
    if (lane < D) {
      float zv = zr[h * D + lane];
      pl = zv * al[h * D + lane];
      pr = zv * ar[h * D + lane];
    }
    #pragma unroll
    for (int off = 32; off; off >>= 1) {
      pl += __shfl_xor(pl, off);
      pr += __shfl_xor(pr, off);
    }
    if (lane == 0) { el[(size_t)wave * H + h] = pl; er[(size_t)wave * H + h] = pr; }
  }
}

// ============================ layer-0 aggregation (R4 structure; bf16 z gather) ============================

__global__ __launch_bounds__(256) void agg0_kernel(
    const int* __restrict__ offs, const int* __restrict__ ssrc,
    const float* __restrict__ el, const float* __restrict__ er,
    const unsigned short* __restrict__ zb, const float* __restrict__ bias,
    float* __restrict__ out, int n) {
  __shared__ float sW[4][16][4];
  __shared__ int   sS[4][16];
  int wid  = threadIdx.x >> 6;
  int lane = threadIdx.x & 63;
  int node = blockIdx.x * 4 + wid;
  if (node >= n) return;
  int c = lane & 3, eoff = lane >> 2, h = lane >> 4;
  int s0 = offs[node], s1 = offs[node + 1];
  float er_c = er[node * 4 + c];

  // pass 1: per-class max
  float m = -INFINITY;
  for (int base = s0; base < s1; base += 16) {
    int cnt = min(16, s1 - base);
    if (eoff < cnt) {
      int esrc = ssrc[base + eoff];
      float v = el[esrc * 4 + c] + er_c;
      v = v > 0.f ? v : 0.2f * v;
      m = fmaxf(m, v);
    }
  }
  m = fmaxf(m, __shfl_xor(m, 4));
  m = fmaxf(m, __shfl_xor(m, 8));
  m = fmaxf(m, __shfl_xor(m, 16));
  m = fmaxf(m, __shfl_xor(m, 32));

  // pass 2: stage weights in LDS, broadcast-read + bf16 gather
  float ssum = 0.f;
  float4 acc = make_float4(0.f, 0.f, 0.f, 0.f);
  for (int base = s0; base < s1; base += 16) {
    int cnt = min(16, s1 - base);
    if (eoff < cnt) {
      int esrc = ssrc[base + eoff];
      float v = el[esrc * 4 + c] + er_c;
      v = v > 0.f ? v : 0.2f * v;
      sW[wid][eoff][c] = expf(v - m);
      if (c == 0) sS[wid][eoff] = esrc;
    }
    for (int j = 0; j < cnt; ++j) {
      float w  = sW[wid][j][h];
      int   sn = sS[wid][j];
      ssum += w;
      const ushort4 zu = *(const ushort4*)(zb + (size_t)sn * 256 + (lane << 2));
      acc.x += w * bf2f(zu.x);
      acc.y += w * bf2f(zu.y);
      acc.z += w * bf2f(zu.z);
      acc.w += w * bf2f(zu.w);
    }
  }

  float inv = (s1 > s0) ? 1.f / ssum : 0.f;
  const float4 b4 = *(const float4*)(bias + (lane << 2));
  float4 o;
  o.x = acc.x * inv + b4.x;
  o.y = acc.y * inv + b4.y;
  o.z = acc.z * inv + b4.z;
  o.w = acc.w * inv + b4.w;
  o.x = o.x > 0.f ? o.x : expm1f(o.x);
  o.y = o.y > 0.f ? o.y : expm1f(o.y);
  o.z = o.z > 0.f ? o.z : expm1f(o.z);
  o.w = o.w > 0.f ? o.w : expm1f(o.w);
  *(float4*)(out + (size_t)node * 256 + (lane << 2)) = o;
}

// ============================ layer-1 aggregation (R5 structure; bf16 z gather) ============================

__global__ __launch_bounds__(256) void agg1_kernel(
    const int* __restrict__ offs, const int* __restrict__ ssrc,
    const float* __restrict__ el, const float* __restrict__ er,
    const unsigned short* __restrict__ zb, const float* __restrict__ bias,
    float* __restrict__ out, int n) {
  __shared__ float sW[4][64];
  __shared__ int   sS[4][64];
  int wid  = threadIdx.x >> 6;
  int lane = threadIdx.x & 63;
  int node = blockIdx.x * 4 + wid;
  if (node >= n) return;
  int s0 = offs[node], s1 = offs[node + 1];
  float ern = er[node];

  float m = -INFINITY;
  for (int base = s0; base < s1; base += 64) {
    int i = base + lane;
    if (i < s1) {
      float v = el[ssrc[i]] + ern;
      v = v > 0.f ? v : 0.2f * v;
      m = fmaxf(m, v);
    }
  }
  m = fmaxf(m, __shfl_xor(m, 1));
  m = fmaxf(m, __shfl_xor(m, 2));
  m = fmaxf(m, __shfl_xor(m, 4));
  m = fmaxf(m, __shfl_xor(m, 8));
  m = fmaxf(m, __shfl_xor(m, 16));
  m = fmaxf(m, __shfl_xor(m, 32));

  float ssum = 0.f, acc = 0.f;
  for (int base = s0; base < s1; base += 64) {
    int cnt = min(64, s1 - base);
    if (lane < cnt) {
      int esrc = ssrc[base + lane];
      float v = el[esrc] + ern;
      v = v > 0.f ? v : 0.2f * v;
      sW[wid][lane] = expf(v - m);
      sS[wid][lane] = esrc;
    }
    for (int j = 0; j < cnt; ++j) {
      float w  = sW[wid][j];
      int   sn = sS[wid][j];
      ssum += w;
      if (lane < 40) acc += w * bf2f(zb[(size_t)sn * 40 + lane]);
    }
  }

  float inv = (s1 > s0) ? 1.f / ssum : 0.f;
  if (lane < 40)
    out[(size_t)node * 40 + lane] = acc * inv + bias[lane];
}

// ============================ launch ============================

extern "C" void kernel_launch(void* const* d_in, const int* in_sizes, int n_in,
                              void* d_out, int out_size, void* d_ws, size_t ws_size,
                              hipStream_t stream) {
  const float* x   = (const float*)d_in[0];
  const int*   src = (const int*)d_in[1];
  const int*   dst = (const int*)d_in[2];
  const float* W0  = (const float*)d_in[3];
  const float* al0 = (const float*)d_in[4];
  const float* ar0 = (const float*)d_in[5];
  const float* b0  = (const float*)d_in[6];
  const float* W1  = (const float*)d_in[7];
  const float* al1 = (const float*)d_in[8];
  const float* ar1 = (const float*)d_in[9];
  const float* b1  = (const float*)d_in[10];
  float* out = (float*)d_out;

  const int N = in_sizes[0] / 256;   // 50000
  const int E = in_sizes[1];         // 800000
  const int NB = (N + 255) / 256;

  char* ws = (char*)d_ws;
  size_t off = 0;
  auto alloc = [&](size_t bytes) {
    void* p = ws + off;
    off = (off + bytes + 255) & ~(size_t)255;
    return p;
  };
  float* z0            = (float*)alloc((size_t)N * 256 * 4);
  unsigned short* z0b  = (unsigned short*)alloc((size_t)N * 256 * 2);
  float* h0            = (float*)alloc((size_t)N * 256 * 4);
  float* z1            = (float*)alloc((size_t)N * 40 * 4);
  unsigned short* z1b  = (unsigned short*)alloc((size_t)N * 40 * 2);
  float* el0  = (float*)alloc((size_t)N * 4 * 4);
  float* er0  = (float*)alloc((size_t)N * 4 * 4);
  float* el1  = (float*)alloc((size_t)N * 4);
  float* er1  = (float*)alloc((size_t)N * 4);
  int* deg    = (int*)alloc((size_t)N * 4);
  int* offs   = (int*)alloc((size_t)(N + 1) * 4);
  int* cursor = (int*)alloc((size_t)N * 4);
  int* bsum   = (int*)alloc((size_t)NB * 4);
  int* boffs  = (int*)alloc((size_t)NB * 4);
  int* ssrc   = (int*)alloc((size_t)E * 4);
  (void)off; (void)ws_size; (void)n_in; (void)out_size;

  // ---- CSR (same graph both layers) ----
  zero_int_kernel<<<(N + 255) / 256, 256, 0, stream>>>(deg, N);
  hist_kernel<<<(E + 255) / 256, 256, 0, stream>>>(dst, deg, E);
  block_sum_kernel<<<NB, 256, 0, stream>>>(deg, bsum, N);
  scan_bsum_kernel<<<1, 1024, 0, stream>>>(bsum, boffs, offs, NB, N);
  write_offsets_kernel<<<NB, 256, 0, stream>>>(deg, boffs, offs, cursor, N);
  build_csr_kernel<<<(E + 255) / 256, 256, 0, stream>>>(src, dst, cursor, ssrc, E);

  // ---- layer 0: GATConv(256 -> 4x64) + ELU ----
  gemm128_kernel<<<dim3((N + 127) / 128, 2), 256, 0, stream>>>(x, W0, z0, z0b, N, 256, 256);
  elr_kernel<4, 64><<<(N + 3) / 4, 256, 0, stream>>>(z0, al0, ar0, el0, er0, N);
  agg0_kernel<<<(N + 3) / 4, 256, 0, stream>>>(offs, ssrc, el0, er0, z0b, b0, h0, N);

  // ---- layer 1: GATConv(256 -> 1x40), head-mean (H=1) ----
  gemm_kernel<<<dim3((N + 63) / 64, 1), 256, 0, stream>>>(h0, W1, z1, z1b, N, 40, 256);
  elr_kernel<1, 40><<<(N + 3) / 4, 256, 0, stream>>>(z1, al1, ar1, el1, er1, N);
  agg1_kernel<<<(N + 3) / 4, 256, 0, stream>>>(offs, ssrc, el1, er1, z1b, b1, out, N);
}

// Round 7
// 455.760 us; speedup vs baseline: 1.9923x; 1.0751x over previous
//
#include <hip/hip_runtime.h>
#include <math.h>

using bf16x8 = __attribute__((ext_vector_type(8))) short;
using f32x4  = __attribute__((ext_vector_type(4))) float;

// ---- bf16 helpers ----
__device__ __forceinline__ unsigned short f2bf(float v) {          // RNE pack
  unsigned int b = __float_as_uint(v);
  unsigned int r = (b + 0x7fffu + ((b >> 16) & 1u)) >> 16;
  return (unsigned short)r;
}
__device__ __forceinline__ float bf2f(unsigned short u) {
  return __uint_as_float(((unsigned int)u) << 16);
}

// ============================ CSR build (proven R5) ============================

__global__ void zero_int_kernel(int* __restrict__ p, int n) {
  int t = blockIdx.x * blockDim.x + threadIdx.x;
  if (t < n) p[t] = 0;
}

__global__ void hist_kernel(const int* __restrict__ dst, int* __restrict__ deg, int E) {
  int t = blockIdx.x * blockDim.x + threadIdx.x;
  if (t < E) atomicAdd(&deg[dst[t]], 1);
}

__global__ void block_sum_kernel(const int* __restrict__ deg, int* __restrict__ bsum, int n) {
  __shared__ int red[4];
  int t = threadIdx.x, i = blockIdx.x * 256 + t;
  int v = (i < n) ? deg[i] : 0;
  #pragma unroll
  for (int off = 32; off; off >>= 1) v += __shfl_xor(v, off);
  if ((t & 63) == 0) red[t >> 6] = v;
  __syncthreads();
  if (t == 0) bsum[blockIdx.x] = red[0] + red[1] + red[2] + red[3];
}

__global__ void scan_bsum_kernel(const int* __restrict__ bsum, int* __restrict__ boffs,
                                 int* __restrict__ offsets, int nb, int n) {
  __shared__ int tmp[1024];
  int t = threadIdx.x;
  int v = (t < nb) ? bsum[t] : 0;
  tmp[t] = v;
  __syncthreads();
  #pragma unroll
  for (int off = 1; off < 1024; off <<= 1) {
    int add = (t >= off) ? tmp[t - off] : 0;
    __syncthreads();
    tmp[t] += add;
    __syncthreads();
  }
  if (t < nb) boffs[t] = tmp[t] - v;
  if (t == 1023) offsets[n] = tmp[1023];
}

__global__ void write_offsets_kernel(const int* __restrict__ deg, const int* __restrict__ boffs,
                                     int* __restrict__ offsets, int* __restrict__ cursor, int n) {
  __shared__ int tmp[256];
  int t = threadIdx.x, i = blockIdx.x * 256 + t;
  int v = (i < n) ? deg[i] : 0;
  tmp[t] = v;
  __syncthreads();
  #pragma unroll
  for (int off = 1; off < 256; off <<= 1) {
    int add = (t >= off) ? tmp[t - off] : 0;
    __syncthreads();
    tmp[t] += add;
    __syncthreads();
  }
  if (i < n) {
    int o = boffs[blockIdx.x] + tmp[t] - v;
    offsets[i] = o;
    cursor[i] = o;
  }
}

__global__ void build_csr_kernel(const int* __restrict__ src, const int* __restrict__ dst,
                                 int* __restrict__ cursor, int* __restrict__ src_sorted, int E) {
  int e = blockIdx.x * blockDim.x + threadIdx.x;
  if (e < E) {
    int p = atomicAdd(&cursor[dst[e]], 1);
    src_sorted[p] = src[e];
  }
}

// ============================ W0 pack: MFMA B-fragment order ============================
// Bp[((t*8 + s)*64 + lane)*8 + j] = bf16( W[(s*32 + (lane>>4)*8 + j)*256 + t*16 + (lane&15)] )
// (B operand of 16x16x32: n = lane&15, k = quad*8+j; k_step s covers k = s*32..s*32+31)

__global__ void pack_w0_kernel(const float* __restrict__ W, unsigned short* __restrict__ Bp) {
  int idx = blockIdx.x * 256 + threadIdx.x;      // 8192 = 16 t * 8 s * 64 lanes
  int lane = idx & 63, s = (idx >> 6) & 7, t = idx >> 9;
  int n = t * 16 + (lane & 15), quad = lane >> 4;
  unsigned short* o = Bp + (size_t)idx * 8;
  #pragma unroll
  for (int j = 0; j < 8; ++j) {
    int k = s * 32 + quad * 8 + j;
    o[j] = f2bf(W[(size_t)k * 256 + n]);
  }
}

// ============================ layer-0 GEMM: bf16 MFMA, no LDS ============================
// Wave computes 16 rows x 256 cols. A fp32 read once, converted in-register.
// Writes bf16 z only (consumers: elr (bf16), agg0 (bf16)).

__global__ __launch_bounds__(256) void gemm0_mfma_kernel(
    const float* __restrict__ A, const unsigned short* __restrict__ Bp,
    unsigned short* __restrict__ Zb, int M) {
  int wid = threadIdx.x >> 6, lane = threadIdx.x & 63;
  int quad = lane >> 4, col16 = lane & 15;
  int m = blockIdx.x * 64 + wid * 16 + col16;    // row this lane supplies to A-frags

  f32x4 acc[16];
  #pragma unroll
  for (int t = 0; t < 16; ++t) acc[t] = {0.f, 0.f, 0.f, 0.f};

  const bf16x8* BpV = (const bf16x8*)Bp;

  for (int s = 0; s < 8; ++s) {                  // k = s*32 .. s*32+31
    bf16x8 af;
    if (m < M) {
      const float* ap = A + (size_t)m * 256 + s * 32 + quad * 8;
      float4 a0 = *(const float4*)ap;
      float4 a1 = *(const float4*)(ap + 4);
      af[0] = (short)f2bf(a0.x); af[1] = (short)f2bf(a0.y);
      af[2] = (short)f2bf(a0.z); af[3] = (short)f2bf(a0.w);
      af[4] = (short)f2bf(a1.x); af[5] = (short)f2bf(a1.y);
      af[6] = (short)f2bf(a1.z); af[7] = (short)f2bf(a1.w);
    } else {
      #pragma unroll
      for (int j = 0; j < 8; ++j) af[j] = 0;
    }
    #pragma unroll
    for (int t = 0; t < 16; ++t) {
      bf16x8 bf = BpV[(t * 8 + s) * 64 + lane];
      acc[t] = __builtin_amdgcn_mfma_f32_16x16x32_bf16(af, bf, acc[t], 0, 0, 0);
    }
  }

  // epilogue: C/D layout col = lane&15, row = quad*4 + reg
  int row0 = blockIdx.x * 64 + wid * 16 + quad * 4;
  #pragma unroll
  for (int r = 0; r < 4; ++r) {
    int row = row0 + r;
    if (row < M) {
      #pragma unroll
      for (int t = 0; t < 16; ++t)
        Zb[(size_t)row * 256 + t * 16 + col16] = f2bf(acc[t][r]);
    }
  }
}

// ============================ GEMM 64-tile fp32 (proven R1) + bf16 aux out ============================

__global__ __launch_bounds__(256) void gemm_kernel(const float* __restrict__ A,
                                                   const float* __restrict__ B,
                                                   float* __restrict__ C,
                                                   unsigned short* __restrict__ Cb,
                                                   int M, int N, int K) {
  __shared__ float As[16][64];
  __shared__ float Bs[16][64];
  int t = threadIdx.x;
  int bm0 = blockIdx.x * 64;
  int bn0 = blockIdx.y * 64;
  int tx = t & 15, ty = t >> 4;
  int tm0 = ty * 4, tn0 = tx * 4;
  float acc[4][4] = {};
  int ar = t >> 2, ac4 = (t & 3) * 4;
  int br = t >> 4, bc4 = (t & 15) * 4;

  for (int k0 = 0; k0 < K; k0 += 16) {
    float4 a4 = make_float4(0.f, 0.f, 0.f, 0.f);
    int arow = bm0 + ar;
    if (arow < M) a4 = *(const float4*)(A + (size_t)arow * K + k0 + ac4);
    As[ac4 + 0][ar] = a4.x; As[ac4 + 1][ar] = a4.y;
    As[ac4 + 2][ar] = a4.z; As[ac4 + 3][ar] = a4.w;

    float4 b4 = make_float4(0.f, 0.f, 0.f, 0.f);
    int bcol = bn0 + bc4;
    if (bcol + 3 < N) b4 = *(const float4*)(B + (size_t)(k0 + br) * N + bcol);
    *(float4*)&Bs[br][bc4] = b4;

    __syncthreads();
    #pragma unroll
    for (int kk = 0; kk < 16; ++kk) {
      float4 av = *(const float4*)&As[kk][tm0];
      float4 bv = *(const float4*)&Bs[kk][tn0];
      acc[0][0] += av.x * bv.x; acc[0][1] += av.x * bv.y; acc[0][2] += av.x * bv.z; acc[0][3] += av.x * bv.w;
      acc[1][0] += av.y * bv.x; acc[1][1] += av.y * bv.y; acc[1][2] += av.y * bv.z; acc[1][3] += av.y * bv.w;
      acc[2][0] += av.z * bv.x; acc[2][1] += av.z * bv.y; acc[2][2] += av.z * bv.z; acc[2][3] += av.z * bv.w;
      acc[3][0] += av.w * bv.x; acc[3][1] += av.w * bv.y; acc[3][2] += av.w * bv.z; acc[3][3] += av.w * bv.w;
    }
    __syncthreads();
  }

  #pragma unroll
  for (int i = 0; i < 4; ++i) {
    int row = bm0 + tm0 + i;
    if (row >= M) break;
    int col = bn0 + tn0;
    if (col + 3 < N) {
      float4 v = make_float4(acc[i][0], acc[i][1], acc[i][2], acc[i][3]);
      *(float4*)(C + (size_t)row * N + col) = v;
      if (Cb) {
        ushort4 u;
        u.x = f2bf(acc[i][0]); u.y = f2bf(acc[i][1]);
        u.z = f2bf(acc[i][2]); u.w = f2bf(acc[i][3]);
        *(ushort4*)(Cb + (size_t)row * N + col) = u;
      }
    } else {
      #pragma unroll
      for (int j = 0; j < 4; ++j)
        if (col + j < N) {
          C[(size_t)row * N + col + j] = acc[i][j];
          if (Cb) Cb[(size_t)row * N + col + j] = f2bf(acc[i][j]);
        }
    }
  }
}

// ============================ attention scalars el/er (bf16 z input) ============================

template<int H, int D>
__global__ void elr_kernel(const unsigned short* __restrict__ z, const float* __restrict__ al,
                           const float* __restrict__ ar, float* __restrict__ el,
                           float* __restrict__ er, int n) {
  int wave = blockIdx.x * (blockDim.x >> 6) + (threadIdx.x >> 6);
  int lane = threadIdx.x & 63;
  if (wave >= n) return;
  const unsigned short* zr = z + (size_t)wave * (H * D);
  #pragma unroll
  for (int h = 0; h < H; ++h) {
    float pl = 0.f, pr = 0.f;
    if (lane < D) {
      float zv = bf2f(zr[h * D + lane]);
      pl = zv * al[h * D + lane];
      pr = zv * ar[h * D + lane];
    }
    #pragma unroll
    for (int off = 32; off; off >>= 1) {
      pl += __shfl_xor(pl, off);
      pr += __shfl_xor(pr, off);
    }
    if (lane == 0) { el[(size_t)wave * H + h] = pl; er[(size_t)wave * H + h] = pr; }
  }
}

// ============================ layer-0 aggregation (proven R6: bf16 gather) ============================

__global__ __launch_bounds__(256) void agg0_kernel(
    const int* __restrict__ offs, const int* __restrict__ ssrc,
    const float* __restrict__ el, const float* __restrict__ er,
    const unsigned short* __restrict__ zb, const float* __restrict__ bias,
    float* __restrict__ out, int n) {
  __shared__ float sW[4][16][4];
  __shared__ int   sS[4][16];
  int wid  = threadIdx.x >> 6;
  int lane = threadIdx.x & 63;
  int node = blockIdx.x * 4 + wid;
  if (node >= n) return;
  int c = lane & 3, eoff = lane >> 2, h = lane >> 4;
  int s0 = offs[node], s1 = offs[node + 1];
  float er_c = er[node * 4 + c];

  float m = -INFINITY;
  for (int base = s0; base < s1; base += 16) {
    int cnt = min(16, s1 - base);
    if (eoff < cnt) {
      int esrc = ssrc[base + eoff];
      float v = el[esrc * 4 + c] + er_c;
      v = v > 0.f ? v : 0.2f * v;
      m = fmaxf(m, v);
    }
  }
  m = fmaxf(m, __shfl_xor(m, 4));
  m = fmaxf(m, __shfl_xor(m, 8));
  m = fmaxf(m, __shfl_xor(m, 16));
  m = fmaxf(m, __shfl_xor(m, 32));

  float ssum = 0.f;
  float4 acc = make_float4(0.f, 0.f, 0.f, 0.f);
  for (int base = s0; base < s1; base += 16) {
    int cnt = min(16, s1 - base);
    if (eoff < cnt) {
      int esrc = ssrc[base + eoff];
      float v = el[esrc * 4 + c] + er_c;
      v = v > 0.f ? v : 0.2f * v;
      sW[wid][eoff][c] = expf(v - m);
      if (c == 0) sS[wid][eoff] = esrc;
    }
    for (int j = 0; j < cnt; ++j) {
      float w  = sW[wid][j][h];
      int   sn = sS[wid][j];
      ssum += w;
      const ushort4 zu = *(const ushort4*)(zb + (size_t)sn * 256 + (lane << 2));
      acc.x += w * bf2f(zu.x);
      acc.y += w * bf2f(zu.y);
      acc.z += w * bf2f(zu.z);
      acc.w += w * bf2f(zu.w);
    }
  }

  float inv = (s1 > s0) ? 1.f / ssum : 0.f;
  const float4 b4 = *(const float4*)(bias + (lane << 2));
  float4 o;
  o.x = acc.x * inv + b4.x;
  o.y = acc.y * inv + b4.y;
  o.z = acc.z * inv + b4.z;
  o.w = acc.w * inv + b4.w;
  o.x = o.x > 0.f ? o.x : expm1f(o.x);
  o.y = o.y > 0.f ? o.y : expm1f(o.y);
  o.z = o.z > 0.f ? o.z : expm1f(o.z);
  o.w = o.w > 0.f ? o.w : expm1f(o.w);
  *(float4*)(out + (size_t)node * 256 + (lane << 2)) = o;
}

// ============================ layer-1 aggregation (proven R6: bf16 gather) ============================

__global__ __launch_bounds__(256) void agg1_kernel(
    const int* __restrict__ offs, const int* __restrict__ ssrc,
    const float* __restrict__ el, const float* __restrict__ er,
    const unsigned short* __restrict__ zb, const float* __restrict__ bias,
    float* __restrict__ out, int n) {
  __shared__ float sW[4][64];
  __shared__ int   sS[4][64];
  int wid  = threadIdx.x >> 6;
  int lane = threadIdx.x & 63;
  int node = blockIdx.x * 4 + wid;
  if (node >= n) return;
  int s0 = offs[node], s1 = offs[node + 1];
  float ern = er[node];

  float m = -INFINITY;
  for (int base = s0; base < s1; base += 64) {
    int i = base + lane;
    if (i < s1) {
      float v = el[ssrc[i]] + ern;
      v = v > 0.f ? v : 0.2f * v;
      m = fmaxf(m, v);
    }
  }
  m = fmaxf(m, __shfl_xor(m, 1));
  m = fmaxf(m, __shfl_xor(m, 2));
  m = fmaxf(m, __shfl_xor(m, 4));
  m = fmaxf(m, __shfl_xor(m, 8));
  m = fmaxf(m, __shfl_xor(m, 16));
  m = fmaxf(m, __shfl_xor(m, 32));

  float ssum = 0.f, acc = 0.f;
  for (int base = s0; base < s1; base += 64) {
    int cnt = min(64, s1 - base);
    if (lane < cnt) {
      int esrc = ssrc[base + lane];
      float v = el[esrc] + ern;
      v = v > 0.f ? v : 0.2f * v;
      sW[wid][lane] = expf(v - m);
      sS[wid][lane] = esrc;
    }
    for (int j = 0; j < cnt; ++j) {
      float w  = sW[wid][j];
      int   sn = sS[wid][j];
      ssum += w;
      if (lane < 40) acc += w * bf2f(zb[(size_t)sn * 40 + lane]);
    }
  }

  float inv = (s1 > s0) ? 1.f / ssum : 0.f;
  if (lane < 40)
    out[(size_t)node * 40 + lane] = acc * inv + bias[lane];
}

// ============================ launch ============================

extern "C" void kernel_launch(void* const* d_in, const int* in_sizes, int n_in,
                              void* d_out, int out_size, void* d_ws, size_t ws_size,
                              hipStream_t stream) {
  const float* x   = (const float*)d_in[0];
  const int*   src = (const int*)d_in[1];
  const int*   dst = (const int*)d_in[2];
  const float* W0  = (const float*)d_in[3];
  const float* al0 = (const float*)d_in[4];
  const float* ar0 = (const float*)d_in[5];
  const float* b0  = (const float*)d_in[6];
  const float* W1  = (const float*)d_in[7];
  const float* al1 = (const float*)d_in[8];
  const float* ar1 = (const float*)d_in[9];
  const float* b1  = (const float*)d_in[10];
  float* out = (float*)d_out;

  const int N = in_sizes[0] / 256;   // 50000
  const int E = in_sizes[1];         // 800000
  const int NB = (N + 255) / 256;

  char* ws = (char*)d_ws;
  size_t off = 0;
  auto alloc = [&](size_t bytes) {
    void* p = ws + off;
    off = (off + bytes + 255) & ~(size_t)255;
    return p;
  };
  unsigned short* z0b = (unsigned short*)alloc((size_t)N * 256 * 2);
  unsigned short* w0p = (unsigned short*)alloc((size_t)16 * 8 * 64 * 8 * 2);  // 128 KB packed W0
  float* h0           = (float*)alloc((size_t)N * 256 * 4);
  float* z1           = (float*)alloc((size_t)N * 40 * 4);
  unsigned short* z1b = (unsigned short*)alloc((size_t)N * 40 * 2);
  float* el0  = (float*)alloc((size_t)N * 4 * 4);
  float* er0  = (float*)alloc((size_t)N * 4 * 4);
  float* el1  = (float*)alloc((size_t)N * 4);
  float* er1  = (float*)alloc((size_t)N * 4);
  int* deg    = (int*)alloc((size_t)N * 4);
  int* offs   = (int*)alloc((size_t)(N + 1) * 4);
  int* cursor = (int*)alloc((size_t)N * 4);
  int* bsum   = (int*)alloc((size_t)NB * 4);
  int* boffs  = (int*)alloc((size_t)NB * 4);
  int* ssrc   = (int*)alloc((size_t)E * 4);
  (void)off; (void)ws_size; (void)n_in; (void)out_size;

  // ---- CSR (same graph both layers) ----
  zero_int_kernel<<<(N + 255) / 256, 256, 0, stream>>>(deg, N);
  hist_kernel<<<(E + 255) / 256, 256, 0, stream>>>(dst, deg, E);
  block_sum_kernel<<<NB, 256, 0, stream>>>(deg, bsum, N);
  scan_bsum_kernel<<<1, 1024, 0, stream>>>(bsum, boffs, offs, NB, N);
  write_offsets_kernel<<<NB, 256, 0, stream>>>(deg, boffs, offs, cursor, N);
  build_csr_kernel<<<(E + 255) / 256, 256, 0, stream>>>(src, dst, cursor, ssrc, E);

  // ---- layer 0: GATConv(256 -> 4x64) + ELU, bf16 MFMA projection ----
  pack_w0_kernel<<<32, 256, 0, stream>>>(W0, w0p);
  gemm0_mfma_kernel<<<(N + 63) / 64, 256, 0, stream>>>(x, w0p, z0b, N);
  elr_kernel<4, 64><<<(N + 3) / 4, 256, 0, stream>>>(z0b, al0, ar0, el0, er0, N);
  agg0_kernel<<<(N + 3) / 4, 256, 0, stream>>>(offs, ssrc, el0, er0, z0b, b0, h0, N);

  // ---- layer 1: GATConv(256 -> 1x40), fp32 GEMM, head-mean (H=1) ----
  gemm_kernel<<<dim3((N + 63) / 64, 1), 256, 0, stream>>>(h0, W1, z1, z1b, N, 40, 256);
  elr_kernel<1, 40><<<(N + 3) / 4, 256, 0, stream>>>(z1b, al1, ar1, el1, er1, N);
  agg1_kernel<<<(N + 3) / 4, 256, 0, stream>>>(offs, ssrc, el1, er1, z1b, b1, out, N);
}

// Round 8
// 408.286 us; speedup vs baseline: 2.2239x; 1.1163x over previous
//
#include <hip/hip_runtime.h>
#include <math.h>

using bf16x8 = __attribute__((ext_vector_type(8))) short;
using f32x4  = __attribute__((ext_vector_type(4))) float;

// ---- bf16 helpers ----
__device__ __forceinline__ unsigned short f2bf(float v) {          // RNE pack
  unsigned int b = __float_as_uint(v);
  unsigned int r = (b + 0x7fffu + ((b >> 16) & 1u)) >> 16;
  return (unsigned short)r;
}
__device__ __forceinline__ float bf2f(unsigned short u) {
  return __uint_as_float(((unsigned int)u) << 16);
}

// ============================ CSR build (proven R5) ============================

__global__ void zero_int_kernel(int* __restrict__ p, int n) {
  int t = blockIdx.x * blockDim.x + threadIdx.x;
  if (t < n) p[t] = 0;
}

__global__ void hist_kernel(const int* __restrict__ dst, int* __restrict__ deg, int E) {
  int t = blockIdx.x * blockDim.x + threadIdx.x;
  if (t < E) atomicAdd(&deg[dst[t]], 1);
}

__global__ void block_sum_kernel(const int* __restrict__ deg, int* __restrict__ bsum, int n) {
  __shared__ int red[4];
  int t = threadIdx.x, i = blockIdx.x * 256 + t;
  int v = (i < n) ? deg[i] : 0;
  #pragma unroll
  for (int off = 32; off; off >>= 1) v += __shfl_xor(v, off);
  if ((t & 63) == 0) red[t >> 6] = v;
  __syncthreads();
  if (t == 0) bsum[blockIdx.x] = red[0] + red[1] + red[2] + red[3];
}

__global__ void scan_bsum_kernel(const int* __restrict__ bsum, int* __restrict__ boffs,
                                 int* __restrict__ offsets, int nb, int n) {
  __shared__ int tmp[1024];
  int t = threadIdx.x;
  int v = (t < nb) ? bsum[t] : 0;
  tmp[t] = v;
  __syncthreads();
  #pragma unroll
  for (int off = 1; off < 1024; off <<= 1) {
    int add = (t >= off) ? tmp[t - off] : 0;
    __syncthreads();
    tmp[t] += add;
    __syncthreads();
  }
  if (t < nb) boffs[t] = tmp[t] - v;
  if (t == 1023) offsets[n] = tmp[1023];
}

__global__ void write_offsets_kernel(const int* __restrict__ deg, const int* __restrict__ boffs,
                                     int* __restrict__ offsets, int* __restrict__ cursor, int n) {
  __shared__ int tmp[256];
  int t = threadIdx.x, i = blockIdx.x * 256 + t;
  int v = (i < n) ? deg[i] : 0;
  tmp[t] = v;
  __syncthreads();
  #pragma unroll
  for (int off = 1; off < 256; off <<= 1) {
    int add = (t >= off) ? tmp[t - off] : 0;
    __syncthreads();
    tmp[t] += add;
    __syncthreads();
  }
  if (i < n) {
    int o = boffs[blockIdx.x] + tmp[t] - v;
    offsets[i] = o;
    cursor[i] = o;
  }
}

__global__ void build_csr_kernel(const int* __restrict__ src, const int* __restrict__ dst,
                                 int* __restrict__ cursor, int* __restrict__ src_sorted, int E) {
  int e = blockIdx.x * blockDim.x + threadIdx.x;
  if (e < E) {
    int p = atomicAdd(&cursor[dst[e]], 1);
    src_sorted[p] = src[e];
  }
}

// ============================ weight packs: MFMA B-fragment order ============================
// Bp[((t*8 + s)*64 + lane)*8 + j] = bf16( W[k*NC + n] ), n = t*16+(lane&15),
// k = s*32 + (lane>>4)*8 + j.  (B operand of 16x16x32: n=lane&15, k=quad*8+j)

__global__ void pack_w0_kernel(const float* __restrict__ W, unsigned short* __restrict__ Bp) {
  int idx = blockIdx.x * 256 + threadIdx.x;      // 8192 = 16 t * 8 s * 64 lanes
  int lane = idx & 63, s = (idx >> 6) & 7, t = idx >> 9;
  int n = t * 16 + (lane & 15), quad = lane >> 4;
  unsigned short* o = Bp + (size_t)idx * 8;
  #pragma unroll
  for (int j = 0; j < 8; ++j) {
    int k = s * 32 + quad * 8 + j;
    o[j] = f2bf(W[(size_t)k * 256 + n]);
  }
}

// W1: [256 K, 40 N], padded to 48 cols (3 tiles). n >= 40 -> 0.
__global__ void pack_w1_kernel(const float* __restrict__ W, unsigned short* __restrict__ Bp) {
  int idx = blockIdx.x * 256 + threadIdx.x;      // 1536 = 3 t * 8 s * 64 lanes
  if (idx >= 1536) return;
  int lane = idx & 63, s = (idx >> 6) & 7, t = idx >> 9;
  int n = t * 16 + (lane & 15), quad = lane >> 4;
  unsigned short* o = Bp + (size_t)idx * 8;
  #pragma unroll
  for (int j = 0; j < 8; ++j) {
    int k = s * 32 + quad * 8 + j;
    o[j] = (n < 40) ? f2bf(W[(size_t)k * 40 + n]) : 0;
  }
}

// ============================ layer-0 GEMM: bf16 MFMA, B staged in LDS ============================
// Grid (ceil(M/128), 2 col-halves). Block = 4 waves (2x2); wave = 64 rows x 64 cols
// = 4x4 acc tiles -> 4 MFMAs per ds_read_b128 (B reuse), barrier-free K-loop.

__global__ __launch_bounds__(256) void gemm0_mfma_kernel(
    const float* __restrict__ A, const unsigned short* __restrict__ Bp,
    unsigned short* __restrict__ Zb, int M) {
  __shared__ unsigned short Bs[32768];           // 64 KB = this col-half of packed W0
  int tid = threadIdx.x;
  int y = blockIdx.y;                            // col half (128 cols)

  {                                              // stage 64 KB: contiguous slice of Bp
    const int4* s4 = (const int4*)(Bp + (size_t)y * 32768);
    int4* d4 = (int4*)Bs;
    #pragma unroll
    for (int i = 0; i < 16; ++i) d4[tid + i * 256] = s4[tid + i * 256];
  }
  __syncthreads();

  int wid = tid >> 6, lane = tid & 63;
  int quad = lane >> 4, col16 = lane & 15;
  int wr = wid >> 1, wc = wid & 1;               // wave position in 2x2
  int rowbase = blockIdx.x * 128 + wr * 64;

  f32x4 acc[4][4];
  #pragma unroll
  for (int rt = 0; rt < 4; ++rt)
    #pragma unroll
    for (int ct = 0; ct < 4; ++ct) acc[rt][ct] = {0.f, 0.f, 0.f, 0.f};

  const bf16x8* BsV = (const bf16x8*)Bs;

  for (int s = 0; s < 8; ++s) {                  // k = s*32 .. s*32+31
    bf16x8 af[4];
    #pragma unroll
    for (int rt = 0; rt < 4; ++rt) {
      int m = rowbase + rt * 16 + col16;
      if (m < M) {
        const float* ap = A + (size_t)m * 256 + s * 32 + quad * 8;
        float4 a0 = *(const float4*)ap;
        float4 a1 = *(const float4*)(ap + 4);
        af[rt][0] = (short)f2bf(a0.x); af[rt][1] = (short)f2bf(a0.y);
        af[rt][2] = (short)f2bf(a0.z); af[rt][3] = (short)f2bf(a0.w);
        af[rt][4] = (short)f2bf(a1.x); af[rt][5] = (short)f2bf(a1.y);
        af[rt][6] = (short)f2bf(a1.z); af[rt][7] = (short)f2bf(a1.w);
      } else {
        #pragma unroll
        for (int j = 0; j < 8; ++j) af[rt][j] = 0;
      }
    }
    #pragma unroll
    for (int ct = 0; ct < 4; ++ct) {
      bf16x8 bf = BsV[((wc * 4 + ct) * 8 + s) * 64 + lane];
      #pragma unroll
      for (int rt = 0; rt < 4; ++rt)
        acc[rt][ct] = __builtin_amdgcn_mfma_f32_16x16x32_bf16(af[rt], bf, acc[rt][ct], 0, 0, 0);
    }
  }

  // epilogue: C/D layout col = lane&15, row = quad*4 + reg
  #pragma unroll
  for (int rt = 0; rt < 4; ++rt) {
    int row0 = rowbase + rt * 16 + quad * 4;
    #pragma unroll
    for (int r = 0; r < 4; ++r) {
      int row = row0 + r;
      if (row < M) {
        #pragma unroll
        for (int ct = 0; ct < 4; ++ct) {
          int col = y * 128 + (wc * 4 + ct) * 16 + col16;
          Zb[(size_t)row * 256 + col] = f2bf(acc[rt][ct][r]);
        }
      }
    }
  }
}

// ============================ layer-1 GEMM: bf16 MFMA, no LDS (B1 = 24 KB, L1-hot) ============================
// Wave = 16 rows x 48 cols (40 real). A = h0b bf16 -> one b128 load per frag.

__global__ __launch_bounds__(256) void gemm1_mfma_kernel(
    const unsigned short* __restrict__ Ab, const unsigned short* __restrict__ Bp,
    unsigned short* __restrict__ Zb, int M) {
  int wid = threadIdx.x >> 6, lane = threadIdx.x & 63;
  int quad = lane >> 4, col16 = lane & 15;
  int m = blockIdx.x * 64 + wid * 16 + col16;

  f32x4 acc[3];
  #pragma unroll
  for (int t = 0; t < 3; ++t) acc[t] = {0.f, 0.f, 0.f, 0.f};

  const bf16x8* BpV = (const bf16x8*)Bp;

  for (int s = 0; s < 8; ++s) {
    bf16x8 af;
    if (m < M) {
      af = *(const bf16x8*)(Ab + (size_t)m * 256 + s * 32 + quad * 8);
    } else {
      #pragma unroll
      for (int j = 0; j < 8; ++j) af[j] = 0;
    }
    #pragma unroll
    for (int t = 0; t < 3; ++t) {
      bf16x8 bf = BpV[(t * 8 + s) * 64 + lane];
      acc[t] = __builtin_amdgcn_mfma_f32_16x16x32_bf16(af, bf, acc[t], 0, 0, 0);
    }
  }

  int row0 = blockIdx.x * 64 + wid * 16 + quad * 4;
  #pragma unroll
  for (int r = 0; r < 4; ++r) {
    int row = row0 + r;
    if (row < M) {
      #pragma unroll
      for (int t = 0; t < 3; ++t) {
        int col = t * 16 + col16;
        if (col < 40) Zb[(size_t)row * 40 + col] = f2bf(acc[t][r]);
      }
    }
  }
}

// ============================ attention scalars el/er (bf16 z input, proven R7) ============================

template<int H, int D>
__global__ void elr_kernel(const unsigned short* __restrict__ z, const float* __restrict__ al,
                           const float* __restrict__ ar, float* __restrict__ el,
                           float* __restrict__ er, int n) {
  int wave = blockIdx.x * (blockDim.x >> 6) + (threadIdx.x >> 6);
  int lane = threadIdx.x & 63;
  if (wave >= n) return;
  const unsigned short* zr = z + (size_t)wave * (H * D);
  #pragma unroll
  for (int h = 0; h < H; ++h) {
    float pl = 0.f, pr = 0.f;
    if (lane < D) {
      float zv = bf2f(zr[h * D + lane]);
      pl = zv * al[h * D + lane];
      pr = zv * ar[h * D + lane];
    }
    #pragma unroll
    for (int off = 32; off; off >>= 1) {
      pl += __shfl_xor(pl, off);
      pr += __shfl_xor(pr, off);
    }
    if (lane == 0) { el[(size_t)wave * H + h] = pl; er[(size_t)wave * H + h] = pr; }
  }
}

// ============================ layer-0 aggregation (proven R6/R7; bf16 out now) ============================

__global__ __launch_bounds__(256) void agg0_kernel(
    const int* __restrict__ offs, const int* __restrict__ ssrc,
    const float* __restrict__ el, const float* __restrict__ er,
    const unsigned short* __restrict__ zb, const float* __restrict__ bias,
    unsigned short* __restrict__ outb, int n) {
  __shared__ float sW[4][16][4];
  __shared__ int   sS[4][16];
  int wid  = threadIdx.x >> 6;
  int lane = threadIdx.x & 63;
  int node = blockIdx.x * 4 + wid;
  if (node >= n) return;
  int c = lane & 3, eoff = lane >> 2, h = lane >> 4;
  int s0 = offs[node], s1 = offs[node + 1];
  float er_c = er[node * 4 + c];

  float m = -INFINITY;
  for (int base = s0; base < s1; base += 16) {
    int cnt = min(16, s1 - base);
    if (eoff < cnt) {
      int esrc = ssrc[base + eoff];
      float v = el[esrc * 4 + c] + er_c;
      v = v > 0.f ? v : 0.2f * v;
      m = fmaxf(m, v);
    }
  }
  m = fmaxf(m, __shfl_xor(m, 4));
  m = fmaxf(m, __shfl_xor(m, 8));
  m = fmaxf(m, __shfl_xor(m, 16));
  m = fmaxf(m, __shfl_xor(m, 32));

  float ssum = 0.f;
  float4 acc = make_float4(0.f, 0.f, 0.f, 0.f);
  for (int base = s0; base < s1; base += 16) {
    int cnt = min(16, s1 - base);
    if (eoff < cnt) {
      int esrc = ssrc[base + eoff];
      float v = el[esrc * 4 + c] + er_c;
      v = v > 0.f ? v : 0.2f * v;
      sW[wid][eoff][c] = expf(v - m);
      if (c == 0) sS[wid][eoff] = esrc;
    }
    for (int j = 0; j < cnt; ++j) {
      float w  = sW[wid][j][h];
      int   sn = sS[wid][j];
      ssum += w;
      const ushort4 zu = *(const ushort4*)(zb + (size_t)sn * 256 + (lane << 2));
      acc.x += w * bf2f(zu.x);
      acc.y += w * bf2f(zu.y);
      acc.z += w * bf2f(zu.z);
      acc.w += w * bf2f(zu.w);
    }
  }

  float inv = (s1 > s0) ? 1.f / ssum : 0.f;
  const float4 b4 = *(const float4*)(bias + (lane << 2));
  float4 o;
  o.x = acc.x * inv + b4.x;
  o.y = acc.y * inv + b4.y;
  o.z = acc.z * inv + b4.z;
  o.w = acc.w * inv + b4.w;
  o.x = o.x > 0.f ? o.x : expm1f(o.x);
  o.y = o.y > 0.f ? o.y : expm1f(o.y);
  o.z = o.z > 0.f ? o.z : expm1f(o.z);
  o.w = o.w > 0.f ? o.w : expm1f(o.w);
  ushort4 u;
  u.x = f2bf(o.x); u.y = f2bf(o.y); u.z = f2bf(o.z); u.w = f2bf(o.w);
  *(ushort4*)(outb + (size_t)node * 256 + (lane << 2)) = u;
}

// ============================ layer-1 aggregation (proven R6/R7) ============================

__global__ __launch_bounds__(256) void agg1_kernel(
    const int* __restrict__ offs, const int* __restrict__ ssrc,
    const float* __restrict__ el, const float* __restrict__ er,
    const unsigned short* __restrict__ zb, const float* __restrict__ bias,
    float* __restrict__ out, int n) {
  __shared__ float sW[4][64];
  __shared__ int   sS[4][64];
  int wid  = threadIdx.x >> 6;
  int lane = threadIdx.x & 63;
  int node = blockIdx.x * 4 + wid;
  if (node >= n) return;
  int s0 = offs[node], s1 = offs[node + 1];
  float ern = er[node];

  float m = -INFINITY;
  for (int base = s0; base < s1; base += 64) {
    int i = base + lane;
    if (i < s1) {
      float v = el[ssrc[i]] + ern;
      v = v > 0.f ? v : 0.2f * v;
      m = fmaxf(m, v);
    }
  }
  m = fmaxf(m, __shfl_xor(m, 1));
  m = fmaxf(m, __shfl_xor(m, 2));
  m = fmaxf(m, __shfl_xor(m, 4));
  m = fmaxf(m, __shfl_xor(m, 8));
  m = fmaxf(m, __shfl_xor(m, 16));
  m = fmaxf(m, __shfl_xor(m, 32));

  float ssum = 0.f, acc = 0.f;
  for (int base = s0; base < s1; base += 64) {
    int cnt = min(64, s1 - base);
    if (lane < cnt) {
      int esrc = ssrc[base + lane];
      float v = el[esrc] + ern;
      v = v > 0.f ? v : 0.2f * v;
      sW[wid][lane] = expf(v - m);
      sS[wid][lane] = esrc;
    }
    for (int j = 0; j < cnt; ++j) {
      float w  = sW[wid][j];
      int   sn = sS[wid][j];
      ssum += w;
      if (lane < 40) acc += w * bf2f(zb[(size_t)sn * 40 + lane]);
    }
  }

  float inv = (s1 > s0) ? 1.f / ssum : 0.f;
  if (lane < 40)
    out[(size_t)node * 40 + lane] = acc * inv + bias[lane];
}

// ============================ launch ============================

extern "C" void kernel_launch(void* const* d_in, const int* in_sizes, int n_in,
                              void* d_out, int out_size, void* d_ws, size_t ws_size,
                              hipStream_t stream) {
  const float* x   = (const float*)d_in[0];
  const int*   src = (const int*)d_in[1];
  const int*   dst = (const int*)d_in[2];
  const float* W0  = (const float*)d_in[3];
  const float* al0 = (const float*)d_in[4];
  const float* ar0 = (const float*)d_in[5];
  const float* b0  = (const float*)d_in[6];
  const float* W1  = (const float*)d_in[7];
  const float* al1 = (const float*)d_in[8];
  const float* ar1 = (const float*)d_in[9];
  const float* b1  = (const float*)d_in[10];
  float* out = (float*)d_out;

  const int N = in_sizes[0] / 256;   // 50000
  const int E = in_sizes[1];         // 800000
  const int NB = (N + 255) / 256;

  char* ws = (char*)d_ws;
  size_t off = 0;
  auto alloc = [&](size_t bytes) {
    void* p = ws + off;
    off = (off + bytes + 255) & ~(size_t)255;
    return p;
  };
  unsigned short* z0b = (unsigned short*)alloc((size_t)N * 256 * 2);
  unsigned short* h0b = (unsigned short*)alloc((size_t)N * 256 * 2);
  unsigned short* z1b = (unsigned short*)alloc((size_t)N * 40 * 2);
  unsigned short* w0p = (unsigned short*)alloc((size_t)16 * 8 * 64 * 8 * 2);  // 128 KB
  unsigned short* w1p = (unsigned short*)alloc((size_t)3 * 8 * 64 * 8 * 2);   // 24 KB
  float* el0  = (float*)alloc((size_t)N * 4 * 4);
  float* er0  = (float*)alloc((size_t)N * 4 * 4);
  float* el1  = (float*)alloc((size_t)N * 4);
  float* er1  = (float*)alloc((size_t)N * 4);
  int* deg    = (int*)alloc((size_t)N * 4);
  int* offs   = (int*)alloc((size_t)(N + 1) * 4);
  int* cursor = (int*)alloc((size_t)N * 4);
  int* bsum   = (int*)alloc((size_t)NB * 4);
  int* boffs  = (int*)alloc((size_t)NB * 4);
  int* ssrc   = (int*)alloc((size_t)E * 4);
  (void)off; (void)ws_size; (void)n_in; (void)out_size;

  // ---- CSR (same graph both layers) + weight packs ----
  zero_int_kernel<<<(N + 255) / 256, 256, 0, stream>>>(deg, N);
  hist_kernel<<<(E + 255) / 256, 256, 0, stream>>>(dst, deg, E);
  block_sum_kernel<<<NB, 256, 0, stream>>>(deg, bsum, N);
  scan_bsum_kernel<<<1, 1024, 0, stream>>>(bsum, boffs, offs, NB, N);
  write_offsets_kernel<<<NB, 256, 0, stream>>>(deg, boffs, offs, cursor, N);
  build_csr_kernel<<<(E + 255) / 256, 256, 0, stream>>>(src, dst, cursor, ssrc, E);
  pack_w0_kernel<<<32, 256, 0, stream>>>(W0, w0p);
  pack_w1_kernel<<<6, 256, 0, stream>>>(W1, w1p);

  // ---- layer 0: GATConv(256 -> 4x64) + ELU ----
  gemm0_mfma_kernel<<<dim3((N + 127) / 128, 2), 256, 0, stream>>>(x, w0p, z0b, N);
  elr_kernel<4, 64><<<(N + 3) / 4, 256, 0, stream>>>(z0b, al0, ar0, el0, er0, N);
  agg0_kernel<<<(N + 3) / 4, 256, 0, stream>>>(offs, ssrc, el0, er0, z0b, b0, h0b, N);

  // ---- layer 1: GATConv(256 -> 1x40), head-mean (H=1) ----
  gemm1_mfma_kernel<<<(N + 63) / 64, 256, 0, stream>>>(h0b, w1p, z1b, N);
  elr_kernel<1, 40><<<(N + 3) / 4, 256, 0, stream>>>(z1b, al1, ar1, el1, er1, N);
  agg1_kernel<<<(N + 3) / 4, 256, 0, stream>>>(offs, ssrc, el1, er1, z1b, b1, out, N);
}

// Round 9
// 378.734 us; speedup vs baseline: 2.3975x; 1.0780x over previous
//
#include <hip/hip_runtime.h>
#include <math.h>

using bf16x8 = __attribute__((ext_vector_type(8))) short;
using f32x4  = __attribute__((ext_vector_type(4))) float;

// ---- bf16 helpers ----
__device__ __forceinline__ unsigned short f2bf(float v) {          // RNE pack
  unsigned int b = __float_as_uint(v);
  unsigned int r = (b + 0x7fffu + ((b >> 16) & 1u)) >> 16;
  return (unsigned short)r;
}
__device__ __forceinline__ float bf2f(unsigned short u) {
  return __uint_as_float(((unsigned int)u) << 16);
}

// ============================ CSR build (proven R5) ============================

__global__ void zero_int_kernel(int* __restrict__ p, int n) {
  int t = blockIdx.x * blockDim.x + threadIdx.x;
  if (t < n) p[t] = 0;
}

__global__ void hist_kernel(const int* __restrict__ dst, int* __restrict__ deg, int E) {
  int t = blockIdx.x * blockDim.x + threadIdx.x;
  if (t < E) atomicAdd(&deg[dst[t]], 1);
}

__global__ void block_sum_kernel(const int* __restrict__ deg, int* __restrict__ bsum, int n) {
  __shared__ int red[4];
  int t = threadIdx.x, i = blockIdx.x * 256 + t;
  int v = (i < n) ? deg[i] : 0;
  #pragma unroll
  for (int off = 32; off; off >>= 1) v += __shfl_xor(v, off);
  if ((t & 63) == 0) red[t >> 6] = v;
  __syncthreads();
  if (t == 0) bsum[blockIdx.x] = red[0] + red[1] + red[2] + red[3];
}

__global__ void scan_bsum_kernel(const int* __restrict__ bsum, int* __restrict__ boffs,
                                 int* __restrict__ offsets, int nb, int n) {
  __shared__ int tmp[1024];
  int t = threadIdx.x;
  int v = (t < nb) ? bsum[t] : 0;
  tmp[t] = v;
  __syncthreads();
  #pragma unroll
  for (int off = 1; off < 1024; off <<= 1) {
    int add = (t >= off) ? tmp[t - off] : 0;
    __syncthreads();
    tmp[t] += add;
    __syncthreads();
  }
  if (t < nb) boffs[t] = tmp[t] - v;
  if (t == 1023) offsets[n] = tmp[1023];
}

__global__ void write_offsets_kernel(const int* __restrict__ deg, const int* __restrict__ boffs,
                                     int* __restrict__ offsets, int* __restrict__ cursor, int n) {
  __shared__ int tmp[256];
  int t = threadIdx.x, i = blockIdx.x * 256 + t;
  int v = (i < n) ? deg[i] : 0;
  tmp[t] = v;
  __syncthreads();
  #pragma unroll
  for (int off = 1; off < 256; off <<= 1) {
    int add = (t >= off) ? tmp[t - off] : 0;
    __syncthreads();
    tmp[t] += add;
    __syncthreads();
  }
  if (i < n) {
    int o = boffs[blockIdx.x] + tmp[t] - v;
    offsets[i] = o;
    cursor[i] = o;
  }
}

__global__ void build_csr_kernel(const int* __restrict__ src, const int* __restrict__ dst,
                                 int* __restrict__ cursor, int* __restrict__ src_sorted, int E) {
  int e = blockIdx.x * blockDim.x + threadIdx.x;
  if (e < E) {
    int p = atomicAdd(&cursor[dst[e]], 1);
    src_sorted[p] = src[e];
  }
}

// ============================ weight pack (W0 + W1 merged): MFMA B-fragment order ============================
// Bp[((t*8+s)*64+lane)*8+j] = bf16(W[k*NC+n]), n=t*16+(lane&15), k=s*32+(lane>>4)*8+j.

__global__ void pack_w_kernel(const float* __restrict__ W0f, unsigned short* __restrict__ Bp0,
                              const float* __restrict__ W1f, unsigned short* __restrict__ Bp1) {
  int idx = blockIdx.x * 256 + threadIdx.x;      // 8192 W0 frags + 1536 W1 frags
  if (idx < 8192) {
    int lane = idx & 63, s = (idx >> 6) & 7, t = idx >> 9;
    int n = t * 16 + (lane & 15), quad = lane >> 4;
    unsigned short* o = Bp0 + (size_t)idx * 8;
    #pragma unroll
    for (int j = 0; j < 8; ++j) {
      int k = s * 32 + quad * 8 + j;
      o[j] = f2bf(W0f[(size_t)k * 256 + n]);
    }
  } else if (idx < 8192 + 1536) {
    int i1 = idx - 8192;
    int lane = i1 & 63, s = (i1 >> 6) & 7, t = i1 >> 9;
    int n = t * 16 + (lane & 15), quad = lane >> 4;
    unsigned short* o = Bp1 + (size_t)i1 * 8;
    #pragma unroll
    for (int j = 0; j < 8; ++j) {
      int k = s * 32 + quad * 8 + j;
      o[j] = (n < 40) ? f2bf(W1f[(size_t)k * 40 + n]) : 0;
    }
  }
}

// ============================ layer-0 GEMM: bf16 MFMA + fused el/er epilogue ============================
// Grid (ceil(M/128), 2 col-halves). Wave = 64 rows x 64 cols = exactly one head's
// columns (head hw = y*2 + wc) -> el0/er0 computed in-epilogue via col16 butterfly.

__global__ __launch_bounds__(256) void gemm0_mfma_kernel(
    const float* __restrict__ A, const unsigned short* __restrict__ Bp,
    unsigned short* __restrict__ Zb,
    const float* __restrict__ al, const float* __restrict__ arr,
    float* __restrict__ el, float* __restrict__ er, int M) {
  __shared__ unsigned short Bs[32768];           // 64 KB = this col-half of packed W0
  int tid = threadIdx.x;
  int y = blockIdx.y;

  {
    const int4* s4 = (const int4*)(Bp + (size_t)y * 32768);
    int4* d4 = (int4*)Bs;
    #pragma unroll
    for (int i = 0; i < 16; ++i) d4[tid + i * 256] = s4[tid + i * 256];
  }
  __syncthreads();

  int wid = tid >> 6, lane = tid & 63;
  int quad = lane >> 4, col16 = lane & 15;
  int wr = wid >> 1, wc = wid & 1;
  int rowbase = blockIdx.x * 128 + wr * 64;

  f32x4 acc[4][4];
  #pragma unroll
  for (int rt = 0; rt < 4; ++rt)
    #pragma unroll
    for (int ct = 0; ct < 4; ++ct) acc[rt][ct] = {0.f, 0.f, 0.f, 0.f};

  const bf16x8* BsV = (const bf16x8*)Bs;

  for (int s = 0; s < 8; ++s) {
    bf16x8 af[4];
    #pragma unroll
    for (int rt = 0; rt < 4; ++rt) {
      int m = rowbase + rt * 16 + col16;
      if (m < M) {
        const float* ap = A + (size_t)m * 256 + s * 32 + quad * 8;
        float4 a0 = *(const float4*)ap;
        float4 a1 = *(const float4*)(ap + 4);
        af[rt][0] = (short)f2bf(a0.x); af[rt][1] = (short)f2bf(a0.y);
        af[rt][2] = (short)f2bf(a0.z); af[rt][3] = (short)f2bf(a0.w);
        af[rt][4] = (short)f2bf(a1.x); af[rt][5] = (short)f2bf(a1.y);
        af[rt][6] = (short)f2bf(a1.z); af[rt][7] = (short)f2bf(a1.w);
      } else {
        #pragma unroll
        for (int j = 0; j < 8; ++j) af[rt][j] = 0;
      }
    }
    #pragma unroll
    for (int ct = 0; ct < 4; ++ct) {
      bf16x8 bf = BsV[((wc * 4 + ct) * 8 + s) * 64 + lane];
      #pragma unroll
      for (int rt = 0; rt < 4; ++rt)
        acc[rt][ct] = __builtin_amdgcn_mfma_f32_16x16x32_bf16(af[rt], bf, acc[rt][ct], 0, 0, 0);
    }
  }

  // ---- epilogue: Zb writes + fused el/er (head hw) ----
  int hw = y * 2 + wc;
  float al_c[4], ar_c[4];
  #pragma unroll
  for (int ct = 0; ct < 4; ++ct) {
    int col = y * 128 + (wc * 4 + ct) * 16 + col16;
    al_c[ct] = al[col];
    ar_c[ct] = arr[col];
  }

  #pragma unroll
  for (int rt = 0; rt < 4; ++rt) {
    int row0 = rowbase + rt * 16 + quad * 4;
    #pragma unroll
    for (int r = 0; r < 4; ++r) {
      int row = row0 + r;
      // Zb write
      if (row < M) {
        #pragma unroll
        for (int ct = 0; ct < 4; ++ct) {
          int col = y * 128 + (wc * 4 + ct) * 16 + col16;
          Zb[(size_t)row * 256 + col] = f2bf(acc[rt][ct][r]);
        }
      }
      // fused el/er: reduce over this head's 64 cols (4 ct regs x 16 col16 lanes)
      float pe = 0.f, pr = 0.f;
      #pragma unroll
      for (int ct = 0; ct < 4; ++ct) {
        float zv = acc[rt][ct][r];
        pe += zv * al_c[ct];
        pr += zv * ar_c[ct];
      }
      pe += __shfl_xor(pe, 1); pr += __shfl_xor(pr, 1);
      pe += __shfl_xor(pe, 2); pr += __shfl_xor(pr, 2);
      pe += __shfl_xor(pe, 4); pr += __shfl_xor(pr, 4);
      pe += __shfl_xor(pe, 8); pr += __shfl_xor(pr, 8);
      if (col16 == 0 && row < M) {
        el[(size_t)row * 4 + hw] = pe;
        er[(size_t)row * 4 + hw] = pr;
      }
    }
  }
}

// ============================ layer-1 GEMM: bf16 MFMA + fused el/er epilogue ============================

__global__ __launch_bounds__(256) void gemm1_mfma_kernel(
    const unsigned short* __restrict__ Ab, const unsigned short* __restrict__ Bp,
    unsigned short* __restrict__ Zb,
    const float* __restrict__ al, const float* __restrict__ arr,
    float* __restrict__ el, float* __restrict__ er, int M) {
  int wid = threadIdx.x >> 6, lane = threadIdx.x & 63;
  int quad = lane >> 4, col16 = lane & 15;
  int m = blockIdx.x * 64 + wid * 16 + col16;

  f32x4 acc[3];
  #pragma unroll
  for (int t = 0; t < 3; ++t) acc[t] = {0.f, 0.f, 0.f, 0.f};

  const bf16x8* BpV = (const bf16x8*)Bp;

  for (int s = 0; s < 8; ++s) {
    bf16x8 af;
    if (m < M) {
      af = *(const bf16x8*)(Ab + (size_t)m * 256 + s * 32 + quad * 8);
    } else {
      #pragma unroll
      for (int j = 0; j < 8; ++j) af[j] = 0;
    }
    #pragma unroll
    for (int t = 0; t < 3; ++t) {
      bf16x8 bf = BpV[(t * 8 + s) * 64 + lane];
      acc[t] = __builtin_amdgcn_mfma_f32_16x16x32_bf16(af, bf, acc[t], 0, 0, 0);
    }
  }

  float al_c[3], ar_c[3];
  #pragma unroll
  for (int t = 0; t < 3; ++t) {
    int col = t * 16 + col16;
    al_c[t] = (col < 40) ? al[col] : 0.f;
    ar_c[t] = (col < 40) ? arr[col] : 0.f;
  }

  int row0 = blockIdx.x * 64 + wid * 16 + quad * 4;
  #pragma unroll
  for (int r = 0; r < 4; ++r) {
    int row = row0 + r;
    if (row < M) {
      #pragma unroll
      for (int t = 0; t < 3; ++t) {
        int col = t * 16 + col16;
        if (col < 40) Zb[(size_t)row * 40 + col] = f2bf(acc[t][r]);
      }
    }
    float pe = 0.f, pr = 0.f;
    #pragma unroll
    for (int t = 0; t < 3; ++t) {
      pe += acc[t][r] * al_c[t];
      pr += acc[t][r] * ar_c[t];
    }
    pe += __shfl_xor(pe, 1); pr += __shfl_xor(pr, 1);
    pe += __shfl_xor(pe, 2); pr += __shfl_xor(pr, 2);
    pe += __shfl_xor(pe, 4); pr += __shfl_xor(pr, 4);
    pe += __shfl_xor(pe, 8); pr += __shfl_xor(pr, 8);
    if (col16 == 0 && row < M) {
      el[row] = pe;
      er[row] = pr;
    }
  }
}

// ============================ layer-0 aggregation: 2 edges/iter, b128 gather ============================
// Staging/softmax passes proven (R4-R8). Gather role: half = lane>>5 (edge parity),
// colg = lane&31 -> 8 cols [colg*8, +8), head h2 = colg>>3. Combine halves at end
// via __shfl_xor(...,32) (proven primitive).

__global__ __launch_bounds__(256) void agg0_kernel(
    const int* __restrict__ offs, const int* __restrict__ ssrc,
    const float* __restrict__ el, const float* __restrict__ er,
    const unsigned short* __restrict__ zb, const float* __restrict__ bias,
    unsigned short* __restrict__ outb, int n) {
  __shared__ float sW[4][16][4];
  __shared__ int   sS[4][16];
  int wid  = threadIdx.x >> 6;
  int lane = threadIdx.x & 63;
  int node = blockIdx.x * 4 + wid;
  if (node >= n) return;
  int c = lane & 3, eoff = lane >> 2;
  int half = lane >> 5, colg = lane & 31, h2 = colg >> 3;
  int s0 = offs[node], s1 = offs[node + 1];
  float er_c = er[node * 4 + c];

  // ---- pass 1: per-class max (scoring role) ----
  float m = -INFINITY;
  for (int base = s0; base < s1; base += 16) {
    int cnt = min(16, s1 - base);
    if (eoff < cnt) {
      int esrc = ssrc[base + eoff];
      float v = el[esrc * 4 + c] + er_c;
      v = v > 0.f ? v : 0.2f * v;
      m = fmaxf(m, v);
    }
  }
  m = fmaxf(m, __shfl_xor(m, 4));
  m = fmaxf(m, __shfl_xor(m, 8));
  m = fmaxf(m, __shfl_xor(m, 16));
  m = fmaxf(m, __shfl_xor(m, 32));

  // ---- pass 2: stage weights; gather 2 edges per iteration ----
  float ssum = 0.f;
  float acc[8] = {0.f, 0.f, 0.f, 0.f, 0.f, 0.f, 0.f, 0.f};
  for (int base = s0; base < s1; base += 16) {
    int cnt = min(16, s1 - base);
    if (eoff < cnt) {
      int esrc = ssrc[base + eoff];
      float v = el[esrc * 4 + c] + er_c;
      v = v > 0.f ? v : 0.2f * v;
      sW[wid][eoff][c] = expf(v - m);
      if (c == 0) sS[wid][eoff] = esrc;
    }
    for (int j = 0; j < cnt; j += 2) {
      int jj = j + half;
      float w = (jj < cnt) ? sW[wid][jj][h2] : 0.f;
      int sn = sS[wid][(jj < cnt) ? jj : (cnt - 1)];
      ssum += w;
      bf16x8 zu = *(const bf16x8*)(zb + (size_t)sn * 256 + (colg << 3));
      #pragma unroll
      for (int i = 0; i < 8; ++i)
        acc[i] += w * bf2f((unsigned short)zu[i]);
    }
  }

  // combine halves
  ssum += __shfl_xor(ssum, 32);
  #pragma unroll
  for (int i = 0; i < 8; ++i) acc[i] += __shfl_xor(acc[i], 32);

  float inv = (s1 > s0) ? 1.f / ssum : 0.f;
  if (half == 0) {
    const float4 b0v = *(const float4*)(bias + (colg << 3));
    const float4 b1v = *(const float4*)(bias + (colg << 3) + 4);
    float bb[8] = {b0v.x, b0v.y, b0v.z, b0v.w, b1v.x, b1v.y, b1v.z, b1v.w};
    bf16x8 u;
    #pragma unroll
    for (int i = 0; i < 8; ++i) {
      float o = acc[i] * inv + bb[i];
      o = o > 0.f ? o : expm1f(o);               // ELU
      u[i] = (short)f2bf(o);
    }
    *(bf16x8*)(outb + (size_t)node * 256 + (colg << 3)) = u;
  }
}

// ============================ layer-1 aggregation (proven R6-R8) ============================

__global__ __launch_bounds__(256) void agg1_kernel(
    const int* __restrict__ offs, const int* __restrict__ ssrc,
    const float* __restrict__ el, const float* __restrict__ er,
    const unsigned short* __restrict__ zb, const float* __restrict__ bias,
    float* __restrict__ out, int n) {
  __shared__ float sW[4][64];
  __shared__ int   sS[4][64];
  int wid  = threadIdx.x >> 6;
  int lane = threadIdx.x & 63;
  int node = blockIdx.x * 4 + wid;
  if (node >= n) return;
  int s0 = offs[node], s1 = offs[node + 1];
  float ern = er[node];

  float m = -INFINITY;
  for (int base = s0; base < s1; base += 64) {
    int i = base + lane;
    if (i < s1) {
      float v = el[ssrc[i]] + ern;
      v = v > 0.f ? v : 0.2f * v;
      m = fmaxf(m, v);
    }
  }
  m = fmaxf(m, __shfl_xor(m, 1));
  m = fmaxf(m, __shfl_xor(m, 2));
  m = fmaxf(m, __shfl_xor(m, 4));
  m = fmaxf(m, __shfl_xor(m, 8));
  m = fmaxf(m, __shfl_xor(m, 16));
  m = fmaxf(m, __shfl_xor(m, 32));

  float ssum = 0.f, acc = 0.f;
  for (int base = s0; base < s1; base += 64) {
    int cnt = min(64, s1 - base);
    if (lane < cnt) {
      int esrc = ssrc[base + lane];
      float v = el[esrc] + ern;
      v = v > 0.f ? v : 0.2f * v;
      sW[wid][lane] = expf(v - m);
      sS[wid][lane] = esrc;
    }
    for (int j = 0; j < cnt; ++j) {
      float w  = sW[wid][j];
      int   sn = sS[wid][j];
      ssum += w;
      if (lane < 40) acc += w * bf2f(zb[(size_t)sn * 40 + lane]);
    }
  }

  float inv = (s1 > s0) ? 1.f / ssum : 0.f;
  if (lane < 40)
    out[(size_t)node * 40 + lane] = acc * inv + bias[lane];
}

// ============================ launch ============================

extern "C" void kernel_launch(void* const* d_in, const int* in_sizes, int n_in,
                              void* d_out, int out_size, void* d_ws, size_t ws_size,
                              hipStream_t stream) {
  const float* x   = (const float*)d_in[0];
  const int*   src = (const int*)d_in[1];
  const int*   dst = (const int*)d_in[2];
  const float* W0  = (const float*)d_in[3];
  const float* al0 = (const float*)d_in[4];
  const float* ar0 = (const float*)d_in[5];
  const float* b0  = (const float*)d_in[6];
  const float* W1  = (const float*)d_in[7];
  const float* al1 = (const float*)d_in[8];
  const float* ar1 = (const float*)d_in[9];
  const float* b1  = (const float*)d_in[10];
  float* out = (float*)d_out;

  const int N = in_sizes[0] / 256;   // 50000
  const int E = in_sizes[1];         // 800000
  const int NB = (N + 255) / 256;

  char* ws = (char*)d_ws;
  size_t off = 0;
  auto alloc = [&](size_t bytes) {
    void* p = ws + off;
    off = (off + bytes + 255) & ~(size_t)255;
    return p;
  };
  unsigned short* z0b = (unsigned short*)alloc((size_t)N * 256 * 2);
  unsigned short* h0b = (unsigned short*)alloc((size_t)N * 256 * 2);
  unsigned short* z1b = (unsigned short*)alloc((size_t)N * 40 * 2);
  unsigned short* w0p = (unsigned short*)alloc((size_t)16 * 8 * 64 * 8 * 2);  // 128 KB
  unsigned short* w1p = (unsigned short*)alloc((size_t)3 * 8 * 64 * 8 * 2);   // 24 KB
  float* el0  = (float*)alloc((size_t)N * 4 * 4);
  float* er0  = (float*)alloc((size_t)N * 4 * 4);
  float* el1  = (float*)alloc((size_t)N * 4);
  float* er1  = (float*)alloc((size_t)N * 4);
  int* deg    = (int*)alloc((size_t)N * 4);
  int* offs   = (int*)alloc((size_t)(N + 1) * 4);
  int* cursor = (int*)alloc((size_t)N * 4);
  int* bsum   = (int*)alloc((size_t)NB * 4);
  int* boffs  = (int*)alloc((size_t)NB * 4);
  int* ssrc   = (int*)alloc((size_t)E * 4);
  (void)off; (void)ws_size; (void)n_in; (void)out_size;

  // ---- CSR (same graph both layers) + weight packs ----
  pack_w_kernel<<<38, 256, 0, stream>>>(W0, w0p, W1, w1p);
  zero_int_kernel<<<(N + 255) / 256, 256, 0, stream>>>(deg, N);
  hist_kernel<<<(E + 255) / 256, 256, 0, stream>>>(dst, deg, E);
  block_sum_kernel<<<NB, 256, 0, stream>>>(deg, bsum, N);
  scan_bsum_kernel<<<1, 1024, 0, stream>>>(bsum, boffs, offs, NB, N);
  write_offsets_kernel<<<NB, 256, 0, stream>>>(deg, boffs, offs, cursor, N);
  build_csr_kernel<<<(E + 255) / 256, 256, 0, stream>>>(src, dst, cursor, ssrc, E);

  // ---- layer 0: GATConv(256 -> 4x64) + ELU ----
  gemm0_mfma_kernel<<<dim3((N + 127) / 128, 2), 256, 0, stream>>>(x, w0p, z0b, al0, ar0, el0, er0, N);
  agg0_kernel<<<(N + 3) / 4, 256, 0, stream>>>(offs, ssrc, el0, er0, z0b, b0, h0b, N);

  // ---- layer 1: GATConv(256 -> 1x40), head-mean (H=1) ----
  gemm1_mfma_kernel<<<(N + 63) / 64, 256, 0, stream>>>(h0b, w1p, z1b, al1, ar1, el1, er1, N);
  agg1_kernel<<<(N + 3) / 4, 256, 0, stream>>>(offs, ssrc, el1, er1, z1b, b1, out, N);
}